// Round 6
// baseline (550.337 us; speedup 1.0000x reference)
//
#include <hip/hip_runtime.h>
#include <stdint.h>

// MultiBoxLoss B=16, P=43008, G=128.
// R6: k_match = fused k_iou (PPI=2, 1344 blocks: R5's PPI=8 -> 9.6% occupancy
//     regression) + k_bp role (R5 version, unchanged: divide-early u64 pack +
//     LDS max tree). Tail collapsed via per-b completion counters
//     (threadfence + atomicAdd): sel1 in k_main's last block, sel2 in k_h2's,
//     sel3+row-fsum in k_h3's. 7 dispatches total.

#define GC 8    // GTs per bp-role block
#define PPT 4   // priors/thread in tail scan kernels
#define PPI 2   // priors/thread in iou role

typedef float v2f __attribute__((ext_vector_type(2)));
__device__ __forceinline__ v2f v2max(v2f a, v2f b) {
  return __builtin_elementwise_max(a, b);
}
__device__ __forceinline__ v2f v2min(v2f a, v2f b) {
  return __builtin_elementwise_min(a, b);
}

__device__ __forceinline__ float sl1(float x) {
  float a = fabsf(x);
  return a < 1.f ? 0.5f * a * a : a - 0.5f;
}

__device__ __forceinline__ double dwave(double v) {
#pragma unroll
  for (int o = 32; o; o >>= 1) v += __shfl_down(v, o);
  return v;
}

__global__ __launch_bounds__(256) void k_match(
    const float* __restrict__ priors, const float* __restrict__ targets,
    float* __restrict__ bto, int* __restrict__ bti,
    unsigned long long* __restrict__ bp, int P, int G, int NIOU, int PT2,
    int NGC, int PC) {
  int tid = threadIdx.x;
  __shared__ float4 sgt[128];
  __shared__ unsigned long long sred[GC * 256];  // 16 KB (bp role)

  if ((int)blockIdx.x < NIOU) {
    // ---- iou role: per-prior best-truth ----
    int b = blockIdx.x / PT2, tile = blockIdx.x % PT2;
    int base = tile * (256 * PPI);
    for (int g = tid; g < G; g += 256) {
      const float* t = targets + ((size_t)b * G + g) * 15;
      sgt[g] = make_float4(t[0], t[1], t[2], t[3]);
    }
    __syncthreads();

    v2f plt[PPI], prb[PPI];
    float pa[PPI], bi[PPI], bu[PPI];
    int bidx[PPI];
#pragma unroll
    for (int k = 0; k < PPI; ++k) {
      int p = base + tid + k * 256;
      int pl = p < P ? p : P - 1;
      float4 pr = ((const float4*)priors)[pl];
      v2f c = {pr.x, pr.y}, h = {pr.z * 0.5f, pr.w * 0.5f};
      plt[k] = c - h; prb[k] = c + h;
      pa[k] = pr.z * pr.w;
      bi[k] = -1.f; bu[k] = 1.f; bidx[k] = 0;
    }
    for (int g = 0; g < G; ++g) {
      float4 T = sgt[g];
      v2f Tlt = {T.x, T.y}, Trb = {T.z, T.w};
      v2f gd = Trb - Tlt;
      float A = gd.x * gd.y;
#pragma unroll
      for (int k = 0; k < PPI; ++k) {
        v2f lt = v2max(Tlt, plt[k]);
        v2f rb = v2min(Trb, prb[k]);
        v2f d = v2max(rb - lt, (v2f)(0.f));
        float inter = d.x * d.y;
        float uni = (A + pa[k]) - inter;
        if (inter * bu[k] > bi[k] * uni) { bi[k] = inter; bu[k] = uni; bidx[k] = g; }
      }
    }
#pragma unroll
    for (int k = 0; k < PPI; ++k) {
      int p = base + tid + k * 256;
      if (p < P) {
        bto[(size_t)b * P + p] = bi[k] / bu[k];
        bti[(size_t)b * P + p] = bidx[k];
      }
    }
  } else {
    // ---- bp role: per-GT best-prior (R5 k_bp, unchanged) ----
    int bc = blockIdx.x - NIOU;
    int pc = bc % PC;
    int gcb = (bc / PC) % NGC;
    int b = bc / (PC * NGC);
    int g0 = gcb * GC;

    if (tid < GC) {
      int g = g0 + tid;
      float4 v = make_float4(0.f, 0.f, 0.f, 0.f);
      if (g < G) {
        const float* t = targets + ((size_t)b * G + g) * 15;
        v = make_float4(t[0], t[1], t[2], t[3]);
      }
      sgt[tid] = v;
    }
    __syncthreads();

    v2f glt[GC], grb[GC];
    float ga[GC];
#pragma unroll
    for (int j = 0; j < GC; ++j) {
      float4 T = sgt[j];
      glt[j] = (v2f){T.x, T.y};
      grb[j] = (v2f){T.z, T.w};
      ga[j] = (T.z - T.x) * (T.w - T.y);
    }

    float bi[GC], bu[GC];
    unsigned bpp[GC];
#pragma unroll
    for (int j = 0; j < GC; ++j) { bi[j] = -1.f; bu[j] = 1.f; bpp[j] = 0; }

    int chunk = (P + PC - 1) / PC;
    int ps = pc * chunk;
    int pe = ps + chunk; if (pe > P) pe = P;

    for (int p = ps + tid; p < pe; p += 256) {
      float4 pr = ((const float4*)priors)[p];
      v2f c = {pr.x, pr.y}, h = {pr.z * 0.5f, pr.w * 0.5f};
      v2f plt = c - h, prb = c + h;
      float pa = pr.z * pr.w;
#pragma unroll
      for (int j = 0; j < GC; ++j) {
        v2f lt = v2max(glt[j], plt);
        v2f rb = v2min(grb[j], prb);
        v2f d = v2max(rb - lt, (v2f)(0.f));
        float inter = d.x * d.y;
        float uni = (ga[j] + pa) - inter;
        if (inter * bu[j] > bi[j] * uni) { bi[j] = inter; bu[j] = uni; bpp[j] = (unsigned)p; }
      }
    }

#pragma unroll
    for (int j = 0; j < GC; ++j) {
      unsigned long long pk = 0ULL;
      if (bi[j] >= 0.f) {
        float iou = bi[j] / bu[j];
        pk = ((unsigned long long)__float_as_uint(iou) << 32) |
             (unsigned)(~bpp[j]);
      }
      sred[j * 256 + tid] = pk;
    }
    __syncthreads();
    {
      int j = tid >> 5, s = tid & 31;
      unsigned long long m = sred[j * 256 + s];
#pragma unroll
      for (int t = 1; t < 8; ++t) {
        unsigned long long v = sred[j * 256 + s + t * 32];
        if (v > m) m = v;
      }
      __syncthreads();
      sred[j * 256 + s] = m;
    }
    __syncthreads();
    if (tid < GC) {
      unsigned long long m = sred[tid * 256];
      for (int s = 1; s < 32; ++s) {
        unsigned long long v = sred[tid * 256 + s];
        if (v > m) m = v;
      }
      int g = g0 + tid;
      if (g < G && m) atomicMax(&bp[(size_t)b * G + g], m);
    }
  }
}

__global__ void k_scatter(const unsigned long long* __restrict__ bp,
                          float* __restrict__ bto, int* __restrict__ bti,
                          int* __restrict__ anyv, int P, int G) {
  int b = blockIdx.x, g = threadIdx.x;
  __shared__ unsigned spp[128];
  __shared__ int s_any;
  if (g == 0) s_any = 0;
  __syncthreads();
  unsigned long long m = bp[(size_t)b * G + g];
  unsigned pp = ~(unsigned)m;
  float val = __uint_as_float((unsigned)(m >> 32));
  bool ok = (m != 0ULL);
  float oldv = 0.f;
  if (ok) oldv = bto[(size_t)b * P + pp];
  spp[g] = ok ? pp : 0xFFFFFFFFu;
  if (ok && val >= 0.2f) s_any = 1;
  __syncthreads();
  bool win = ok;
  for (int g2 = g + 1; g2 < G; ++g2)
    if (spp[g2] == pp) win = false;
  if (win) {
    bto[(size_t)b * P + pp] = (val >= 0.2f) ? 2.0f : oldv;
    bti[(size_t)b * P + pp] = g;
  }
  __syncthreads();
  if (g == 0) anyv[b] = s_any;
}

__global__ __launch_bounds__(256) void k_main(
    const float* __restrict__ loc, const float* __restrict__ conf,
    const float* __restrict__ lm, const float* __restrict__ priors,
    const float* __restrict__ targets, const float* __restrict__ bto,
    const int* __restrict__ bti, const int* __restrict__ anyv,
    float* __restrict__ mine, unsigned* __restrict__ h1,
    double* __restrict__ pll, double* __restrict__ pllm,
    double* __restrict__ plc, int* __restrict__ pnp, int* __restrict__ cnt1,
    int* __restrict__ num_pos, int* __restrict__ pfx1, int* __restrict__ k1,
    int P, int G, int PT) {
  int b = blockIdx.x / PT, tile = blockIdx.x % PT;
  int tid = threadIdx.x;
  int p = tile * 256 + tid;

  __shared__ float st[128 * 15];
  __shared__ unsigned hist[1024];
  __shared__ double rs[12];
  __shared__ int ri[4];
  __shared__ int slast;

  for (int i = tid; i < G * 15; i += 256) st[i] = targets[(size_t)b * G * 15 + i];
  for (int i = tid; i < 1024; i += 256) hist[i] = 0;
  __syncthreads();

  double ll = 0, llm = 0, lc = 0;
  int np = 0;
  if (p < P) {
    size_t idx = (size_t)b * P + p;
    int av = anyv[b];
    float ov = bto[idx];
    int ti = bti[idx];
    bool pos = av && (ov >= 0.35f);

    float2 c = ((const float2*)conf)[idx];
    float mx = fmaxf(c.x, c.y);
    float lse = mx + logf(expf(c.x - mx) + expf(c.y - mx));
    float ce = lse - (pos ? c.y : c.x);
    float mv = pos ? 0.f : ce;
    mine[idx] = mv;
    atomicAdd(&hist[__float_as_uint(mv) >> 21], 1u);

    if (pos) {
      np = 1;
      lc = (double)ce;
      float4 pr = ((const float4*)priors)[p];
      const float* t = st + ti * 15;
      float dx = 0.1f * pr.z, dy = 0.1f * pr.w;
      float gx = ((t[0] + t[2]) * 0.5f - pr.x) / dx;
      float gy = ((t[1] + t[3]) * 0.5f - pr.y) / dy;
      float gw = logf((t[2] - t[0]) / pr.z) * 5.0f;
      float gh = logf((t[3] - t[1]) / pr.w) * 5.0f;
      float4 ld = ((const float4*)loc)[idx];
      ll = (double)(sl1(ld.x - gx) + sl1(ld.y - gy) + sl1(ld.z - gw) +
                    sl1(ld.w - gh));
      const float2* lmd = (const float2*)lm + idx * 5;
      float s = 0.f;
#pragma unroll
      for (int j = 0; j < 5; ++j) {
        float2 lv = lmd[j];
        float ex = (t[4 + 2 * j] - pr.x) / dx;
        float ey = (t[5 + 2 * j] - pr.y) / dy;
        s += sl1(lv.x - ex) + sl1(lv.y - ey);
      }
      llm = (double)s;
    }
  }

  ll = dwave(ll);
  llm = dwave(llm);
  lc = dwave(lc);
#pragma unroll
  for (int o = 32; o; o >>= 1) np += __shfl_down(np, o);
  int lane = tid & 63, wid = tid >> 6;
  if (lane == 0) { rs[wid] = ll; rs[4 + wid] = llm; rs[8 + wid] = lc; ri[wid] = np; }
  __syncthreads();
  if (tid == 0) {
    pll[blockIdx.x] = rs[0] + rs[1] + rs[2] + rs[3];
    pllm[blockIdx.x] = rs[4] + rs[5] + rs[6] + rs[7];
    plc[blockIdx.x] = rs[8] + rs[9] + rs[10] + rs[11];
    pnp[blockIdx.x] = ri[0] + ri[1] + ri[2] + ri[3];
  }
  for (int i = tid; i < 1024; i += 256)
    if (hist[i]) atomicAdd(&h1[(size_t)b * 1024 + i], hist[i]);

  // ---- completion counter: last block of this b runs sel1 ----
  __syncthreads();
  __threadfence();
  if (tid == 0) slast = (atomicAdd(&cnt1[b], 1) == PT - 1) ? 1 : 0;
  __syncthreads();
  if (!slast) return;
  __threadfence();

  __shared__ int sn[256];
  int n = 0;
  for (int i = tid; i < PT; i += 256) n += pnp[b * PT + i];
  sn[tid] = n;
  __syncthreads();
  for (int off = 128; off; off >>= 1) {
    if (tid < off) sn[tid] += sn[tid + off];
    __syncthreads();
  }
  int npos = sn[0];
  if (tid == 0) num_pos[b] = npos;

  const unsigned* h = h1 + (size_t)b * 1024;
  __shared__ unsigned S[256];
  unsigned p0 = h[tid * 4], p1 = h[tid * 4 + 1], p2 = h[tid * 4 + 2],
           p3 = h[tid * 4 + 3];
  S[tid] = p0 + p1 + p2 + p3;
  __syncthreads();
  for (int off = 1; off < 256; off <<= 1) {
    unsigned add = (tid + off < 256) ? S[tid + off] : 0;
    __syncthreads();
    S[tid] += add;
    __syncthreads();
  }
  long long k = 7LL * (long long)npos;
  long long cap = P - 1;
  if (k > cap) k = cap;
  int cnt = __syncthreads_count(k > 0 && (long long)S[tid] >= k);
  if (cnt == 0) {
    if (tid == 0) { pfx1[b] = -1; k1[b] = 0; }
    return;
  }
  int seg = cnt - 1;
  if (tid == seg) {
    long long cum = (seg + 1 < 256) ? (long long)S[seg + 1] : 0;
    unsigned hv[4] = {p0, p1, p2, p3};
    int bin = seg * 4;
    for (int j = 3; j >= 0; --j) {
      if (cum + hv[j] >= k) { bin = seg * 4 + j; break; }
      cum += hv[j];
    }
    pfx1[b] = bin;
    k1[b] = (int)(k - cum);
  }
}

__global__ __launch_bounds__(256) void k_h2(const float* __restrict__ mine,
                                            const int* __restrict__ pfx1,
                                            const int* __restrict__ k1,
                                            unsigned* __restrict__ h2,
                                            int* __restrict__ cnt2,
                                            int* __restrict__ pfx21,
                                            int* __restrict__ k2, int P,
                                            int PT4) {
  int b = blockIdx.x / PT4;
  int base = (blockIdx.x % PT4) * (256 * PPT) + threadIdx.x;
  int tid = threadIdx.x;
  __shared__ unsigned hist[2048];
  __shared__ int slast;
  for (int i = tid; i < 2048; i += 256) hist[i] = 0;
  __syncthreads();
  int pf = pfx1[b];
#pragma unroll
  for (int k = 0; k < PPT; ++k) {
    int p = base + k * 256;
    if (p < P) {
      unsigned bits = __float_as_uint(mine[(size_t)b * P + p]);
      if ((int)(bits >> 21) == pf) atomicAdd(&hist[(bits >> 10) & 2047], 1u);
    }
  }
  __syncthreads();
  for (int i = tid; i < 2048; i += 256)
    if (hist[i]) atomicAdd(&h2[(size_t)b * 2048 + i], hist[i]);

  __syncthreads();
  __threadfence();
  if (tid == 0) slast = (atomicAdd(&cnt2[b], 1) == PT4 - 1) ? 1 : 0;
  __syncthreads();
  if (!slast) return;
  __threadfence();

  const unsigned* h = h2 + (size_t)b * 2048;
  __shared__ unsigned S[256];
  unsigned hv[8];
  unsigned s = 0;
#pragma unroll
  for (int j = 0; j < 8; ++j) { hv[j] = h[tid * 8 + j]; s += hv[j]; }
  S[tid] = s;
  __syncthreads();
  for (int off = 1; off < 256; off <<= 1) {
    unsigned add = (tid + off < 256) ? S[tid + off] : 0;
    __syncthreads();
    S[tid] += add;
    __syncthreads();
  }
  long long k = (long long)k1[b];
  int cnt = __syncthreads_count(pf >= 0 && (long long)S[tid] >= k);
  if (cnt == 0) {
    if (tid == 0) { pfx21[b] = -1; k2[b] = 0; }
    return;
  }
  int seg = cnt - 1;
  if (tid == seg) {
    long long cum = (seg + 1 < 256) ? (long long)S[seg + 1] : 0;
    int bin = seg * 8;
    for (int j = 7; j >= 0; --j) {
      if (cum + hv[j] >= k) { bin = seg * 8 + j; break; }
      cum += hv[j];
    }
    pfx21[b] = (pf << 11) | bin;
    k2[b] = (int)(k - cum);
  }
}

__global__ __launch_bounds__(256) void k_h3(const float* __restrict__ mine,
                                            const int* __restrict__ pfx21,
                                            const int* __restrict__ k2,
                                            unsigned* __restrict__ h3,
                                            int* __restrict__ cnt3,
                                            double* __restrict__ pfs_b, int P,
                                            int PT4) {
  int b = blockIdx.x / PT4;
  int base = (blockIdx.x % PT4) * (256 * PPT) + threadIdx.x;
  int tid = threadIdx.x;
  __shared__ unsigned hist[1024];
  __shared__ int slast;
  for (int i = tid; i < 1024; i += 256) hist[i] = 0;
  __syncthreads();
  int pf = pfx21[b];
#pragma unroll
  for (int k = 0; k < PPT; ++k) {
    int p = base + k * 256;
    if (p < P) {
      unsigned bits = __float_as_uint(mine[(size_t)b * P + p]);
      if ((int)(bits >> 10) == pf) atomicAdd(&hist[bits & 1023], 1u);
    }
  }
  __syncthreads();
  for (int i = tid; i < 1024; i += 256)
    if (hist[i]) atomicAdd(&h3[(size_t)b * 1024 + i], hist[i]);

  __syncthreads();
  __threadfence();
  if (tid == 0) slast = (atomicAdd(&cnt3[b], 1) == PT4 - 1) ? 1 : 0;
  __syncthreads();
  if (!slast) return;
  __threadfence();

  // sel3: find threshold bits tb + tie contribution
  const unsigned* h = h3 + (size_t)b * 1024;
  __shared__ unsigned S[256];
  __shared__ unsigned stb;
  __shared__ double stie;
  unsigned p0 = h[tid * 4], p1 = h[tid * 4 + 1], p2 = h[tid * 4 + 2],
           p3 = h[tid * 4 + 3];
  S[tid] = p0 + p1 + p2 + p3;
  if (tid == 0) { stb = 0xFFFFFFFFu; stie = 0.0; }
  __syncthreads();
  for (int off = 1; off < 256; off <<= 1) {
    unsigned add = (tid + off < 256) ? S[tid + off] : 0;
    __syncthreads();
    S[tid] += add;
    __syncthreads();
  }
  long long k = (long long)k2[b];
  int cnt = __syncthreads_count(pf >= 0 && (long long)S[tid] >= k);
  if (cnt > 0) {
    int seg = cnt - 1;
    if (tid == seg) {
      long long cum = (seg + 1 < 256) ? (long long)S[seg + 1] : 0;
      unsigned hv[4] = {p0, p1, p2, p3};
      int bin = seg * 4;
      for (int j = 3; j >= 0; --j) {
        if (cum + hv[j] >= k) { bin = seg * 4 + j; break; }
        cum += hv[j];
      }
      unsigned tb = ((unsigned)pf << 10) | (unsigned)bin;
      stb = tb;
      stie = (double)(k - cum) * (double)__uint_as_float(tb);
    }
  }
  __syncthreads();
  // row sum of mine strictly above threshold
  unsigned tb = stb;
  double v = 0.0;
  for (int i = tid; i < P; i += 256) {
    unsigned bits = __float_as_uint(mine[(size_t)b * P + i]);
    if (bits > tb) v += (double)__uint_as_float(bits);
  }
  v = dwave(v);
  __shared__ double rs[4];
  int lane = tid & 63, wid = tid >> 6;
  if (lane == 0) rs[wid] = v;
  __syncthreads();
  if (tid == 0) pfs_b[b] = rs[0] + rs[1] + rs[2] + rs[3] + stie;
}

__global__ __launch_bounds__(256) void k_fin(
    const double* __restrict__ pll, const double* __restrict__ pllm,
    const double* __restrict__ plc, const double* __restrict__ pfs_b,
    const int* __restrict__ num_pos, float* __restrict__ out, int NBm, int B) {
  int tid = threadIdx.x;
  double a = 0, c = 0, d = 0, f = 0, n = 0;
  for (int i = tid; i < NBm; i += 256) { a += pll[i]; c += pllm[i]; d += plc[i]; }
  for (int i = tid; i < B; i += 256) { f += pfs_b[i]; n += (double)num_pos[i]; }
  a = dwave(a); c = dwave(c); d = dwave(d); f = dwave(f); n = dwave(n);
  __shared__ double rs[5 * 4];
  int lane = tid & 63, wid = tid >> 6;
  if (lane == 0) {
    rs[wid] = a; rs[4 + wid] = c; rs[8 + wid] = d;
    rs[12 + wid] = f; rs[16 + wid] = n;
  }
  __syncthreads();
  if (tid == 0) {
    double A = rs[0] + rs[1] + rs[2] + rs[3];
    double C = rs[4] + rs[5] + rs[6] + rs[7];
    double D = rs[8] + rs[9] + rs[10] + rs[11];
    double F = rs[12] + rs[13] + rs[14] + rs[15];
    double N = rs[16] + rs[17] + rs[18] + rs[19];
    if (N < 1.0) N = 1.0;
    out[0] = (float)(A / N);
    out[1] = (float)((D + F) / N);
    out[2] = (float)(C / N);
  }
}

extern "C" void kernel_launch(void* const* d_in, const int* in_sizes, int n_in,
                              void* d_out, int out_size, void* d_ws,
                              size_t ws_size, hipStream_t stream) {
  const float* loc = (const float*)d_in[0];
  const float* conf = (const float*)d_in[1];
  const float* lm = (const float*)d_in[2];
  const float* priors = (const float*)d_in[3];
  const float* targets = (const float*)d_in[4];

  int P = in_sizes[3] / 4;
  int B = in_sizes[0] / (4 * P);
  int G = in_sizes[4] / (15 * B);
  int PT = (P + 255) / 256;
  int PT2 = (P + 256 * PPI - 1) / (256 * PPI);
  int PT4 = (P + 256 * PPT - 1) / (256 * PPT);
  int NBm = B * PT;
  int NGC = (G + GC - 1) / GC;
  int PC = 8;
  int NIOU = B * PT2;
  int NBP = B * NGC * PC;

  char* w = (char*)d_ws;
  size_t off = 0;
  // ---- zeroed region ----
  unsigned long long* bp = (unsigned long long*)(w + off);
  off += (size_t)B * G * 8;
  int* ctrl = (int*)(w + off);
  off += (size_t)(10 * B) * 4;
  int* anyv = ctrl;
  int* num_pos = ctrl + B;
  int* pfx1 = ctrl + 2 * B;
  int* k1 = ctrl + 3 * B;
  int* pfx21 = ctrl + 4 * B;
  int* k2 = ctrl + 5 * B;
  int* cnt1 = ctrl + 6 * B;
  int* cnt2 = ctrl + 7 * B;
  int* cnt3 = ctrl + 8 * B;
  unsigned* h1 = (unsigned*)(w + off);
  off += (size_t)B * 1024 * 4;
  unsigned* h2 = (unsigned*)(w + off);
  off += (size_t)B * 2048 * 4;
  unsigned* h3 = (unsigned*)(w + off);
  off += (size_t)B * 1024 * 4;
  size_t clear_bytes = off;
  // ---- non-zeroed region (written unconditionally) ----
  off = (off + 255) & ~(size_t)255;
  float* bto = (float*)(w + off);
  off += (size_t)B * P * 4;
  int* bti = (int*)(w + off);
  off += (size_t)B * P * 4;
  float* mine = (float*)(w + off);
  off += (size_t)B * P * 4;
  double* pll = (double*)(w + off);
  off += (size_t)NBm * 8;
  double* pllm = (double*)(w + off);
  off += (size_t)NBm * 8;
  double* plc = (double*)(w + off);
  off += (size_t)NBm * 8;
  double* pfs_b = (double*)(w + off);
  off += (size_t)B * 8;
  int* pnp = (int*)(w + off);
  off += (size_t)NBm * 4;

  hipMemsetAsync(d_ws, 0, clear_bytes, stream);

  k_match<<<NIOU + NBP, 256, 0, stream>>>(priors, targets, bto, bti, bp, P, G,
                                          NIOU, PT2, NGC, PC);
  k_scatter<<<B, G, 0, stream>>>(bp, bto, bti, anyv, P, G);
  k_main<<<B * PT, 256, 0, stream>>>(loc, conf, lm, priors, targets, bto, bti,
                                     anyv, mine, h1, pll, pllm, plc, pnp, cnt1,
                                     num_pos, pfx1, k1, P, G, PT);
  k_h2<<<B * PT4, 256, 0, stream>>>(mine, pfx1, k1, h2, cnt2, pfx21, k2, P,
                                    PT4);
  k_h3<<<B * PT4, 256, 0, stream>>>(mine, pfx21, k2, h3, cnt3, pfs_b, P, PT4);
  k_fin<<<1, 256, 0, stream>>>(pll, pllm, plc, pfs_b, num_pos, (float*)d_out,
                               NBm, B);
}

// Round 7
// 221.309 us; speedup vs baseline: 2.4867x; 2.4867x over previous
//
#include <hip/hip_runtime.h>
#include <stdint.h>

// MultiBoxLoss B=16, P=43008, G=128.
// R7: revert R6's completion-counter fences (device-scope __threadfence per
//     block = cross-XCD L2 flush storm, k_main 15->240us). Back to R5's
//     multi-dispatch tail (kernel boundary IS the cheap global barrier).
//     Keep R6's fused k_match (iou role PPI=2 + bp role, one dispatch).

#define GC 8    // GTs per bp-role block
#define PPT 4   // priors/thread in tail scan kernels
#define PPI 2   // priors/thread in iou role

typedef float v2f __attribute__((ext_vector_type(2)));
__device__ __forceinline__ v2f v2max(v2f a, v2f b) {
  return __builtin_elementwise_max(a, b);
}
__device__ __forceinline__ v2f v2min(v2f a, v2f b) {
  return __builtin_elementwise_min(a, b);
}

__device__ __forceinline__ float sl1(float x) {
  float a = fabsf(x);
  return a < 1.f ? 0.5f * a * a : a - 0.5f;
}

__device__ __forceinline__ double dwave(double v) {
#pragma unroll
  for (int o = 32; o; o >>= 1) v += __shfl_down(v, o);
  return v;
}

__global__ __launch_bounds__(256) void k_match(
    const float* __restrict__ priors, const float* __restrict__ targets,
    float* __restrict__ bto, int* __restrict__ bti,
    unsigned long long* __restrict__ bp, int P, int G, int NIOU, int PT2,
    int NGC, int PC) {
  int tid = threadIdx.x;
  __shared__ float4 sgt[128];
  __shared__ unsigned long long sred[GC * 256];  // 16 KB (bp role)

  if ((int)blockIdx.x < NIOU) {
    // ---- iou role: per-prior best-truth ----
    int b = blockIdx.x / PT2, tile = blockIdx.x % PT2;
    int base = tile * (256 * PPI);
    for (int g = tid; g < G; g += 256) {
      const float* t = targets + ((size_t)b * G + g) * 15;
      sgt[g] = make_float4(t[0], t[1], t[2], t[3]);
    }
    __syncthreads();

    v2f plt[PPI], prb[PPI];
    float pa[PPI], bi[PPI], bu[PPI];
    int bidx[PPI];
#pragma unroll
    for (int k = 0; k < PPI; ++k) {
      int p = base + tid + k * 256;
      int pl = p < P ? p : P - 1;
      float4 pr = ((const float4*)priors)[pl];
      v2f c = {pr.x, pr.y}, h = {pr.z * 0.5f, pr.w * 0.5f};
      plt[k] = c - h; prb[k] = c + h;
      pa[k] = pr.z * pr.w;
      bi[k] = -1.f; bu[k] = 1.f; bidx[k] = 0;
    }
    for (int g = 0; g < G; ++g) {
      float4 T = sgt[g];
      v2f Tlt = {T.x, T.y}, Trb = {T.z, T.w};
      v2f gd = Trb - Tlt;
      float A = gd.x * gd.y;
#pragma unroll
      for (int k = 0; k < PPI; ++k) {
        v2f lt = v2max(Tlt, plt[k]);
        v2f rb = v2min(Trb, prb[k]);
        v2f d = v2max(rb - lt, (v2f)(0.f));
        float inter = d.x * d.y;
        float uni = (A + pa[k]) - inter;
        if (inter * bu[k] > bi[k] * uni) { bi[k] = inter; bu[k] = uni; bidx[k] = g; }
      }
    }
#pragma unroll
    for (int k = 0; k < PPI; ++k) {
      int p = base + tid + k * 256;
      if (p < P) {
        bto[(size_t)b * P + p] = bi[k] / bu[k];
        bti[(size_t)b * P + p] = bidx[k];
      }
    }
  } else {
    // ---- bp role: per-GT best-prior ----
    int bc = blockIdx.x - NIOU;
    int pc = bc % PC;
    int gcb = (bc / PC) % NGC;
    int b = bc / (PC * NGC);
    int g0 = gcb * GC;

    if (tid < GC) {
      int g = g0 + tid;
      float4 v = make_float4(0.f, 0.f, 0.f, 0.f);
      if (g < G) {
        const float* t = targets + ((size_t)b * G + g) * 15;
        v = make_float4(t[0], t[1], t[2], t[3]);
      }
      sgt[tid] = v;
    }
    __syncthreads();

    v2f glt[GC], grb[GC];
    float ga[GC];
#pragma unroll
    for (int j = 0; j < GC; ++j) {
      float4 T = sgt[j];
      glt[j] = (v2f){T.x, T.y};
      grb[j] = (v2f){T.z, T.w};
      ga[j] = (T.z - T.x) * (T.w - T.y);
    }

    float bi[GC], bu[GC];
    unsigned bpp[GC];
#pragma unroll
    for (int j = 0; j < GC; ++j) { bi[j] = -1.f; bu[j] = 1.f; bpp[j] = 0; }

    int chunk = (P + PC - 1) / PC;
    int ps = pc * chunk;
    int pe = ps + chunk; if (pe > P) pe = P;

    for (int p = ps + tid; p < pe; p += 256) {
      float4 pr = ((const float4*)priors)[p];
      v2f c = {pr.x, pr.y}, h = {pr.z * 0.5f, pr.w * 0.5f};
      v2f plt = c - h, prb = c + h;
      float pa = pr.z * pr.w;
#pragma unroll
      for (int j = 0; j < GC; ++j) {
        v2f lt = v2max(glt[j], plt);
        v2f rb = v2min(grb[j], prb);
        v2f d = v2max(rb - lt, (v2f)(0.f));
        float inter = d.x * d.y;
        float uni = (ga[j] + pa) - inter;
        if (inter * bu[j] > bi[j] * uni) { bi[j] = inter; bu[j] = uni; bpp[j] = (unsigned)p; }
      }
    }

#pragma unroll
    for (int j = 0; j < GC; ++j) {
      unsigned long long pk = 0ULL;
      if (bi[j] >= 0.f) {
        float iou = bi[j] / bu[j];
        pk = ((unsigned long long)__float_as_uint(iou) << 32) |
             (unsigned)(~bpp[j]);
      }
      sred[j * 256 + tid] = pk;
    }
    __syncthreads();
    {
      int j = tid >> 5, s = tid & 31;
      unsigned long long m = sred[j * 256 + s];
#pragma unroll
      for (int t = 1; t < 8; ++t) {
        unsigned long long v = sred[j * 256 + s + t * 32];
        if (v > m) m = v;
      }
      __syncthreads();
      sred[j * 256 + s] = m;
    }
    __syncthreads();
    if (tid < GC) {
      unsigned long long m = sred[tid * 256];
      for (int s = 1; s < 32; ++s) {
        unsigned long long v = sred[tid * 256 + s];
        if (v > m) m = v;
      }
      int g = g0 + tid;
      if (g < G && m) atomicMax(&bp[(size_t)b * G + g], m);
    }
  }
}

__global__ void k_scatter(const unsigned long long* __restrict__ bp,
                          float* __restrict__ bto, int* __restrict__ bti,
                          int* __restrict__ anyv, int P, int G) {
  int b = blockIdx.x, g = threadIdx.x;
  __shared__ unsigned spp[128];
  __shared__ int s_any;
  if (g == 0) s_any = 0;
  __syncthreads();
  unsigned long long m = bp[(size_t)b * G + g];
  unsigned pp = ~(unsigned)m;
  float val = __uint_as_float((unsigned)(m >> 32));
  bool ok = (m != 0ULL);
  float oldv = 0.f;
  if (ok) oldv = bto[(size_t)b * P + pp];
  spp[g] = ok ? pp : 0xFFFFFFFFu;
  if (ok && val >= 0.2f) s_any = 1;
  __syncthreads();
  bool win = ok;
  for (int g2 = g + 1; g2 < G; ++g2)
    if (spp[g2] == pp) win = false;
  if (win) {
    bto[(size_t)b * P + pp] = (val >= 0.2f) ? 2.0f : oldv;
    bti[(size_t)b * P + pp] = g;
  }
  __syncthreads();
  if (g == 0) anyv[b] = s_any;
}

__global__ __launch_bounds__(256) void k_main(
    const float* __restrict__ loc, const float* __restrict__ conf,
    const float* __restrict__ lm, const float* __restrict__ priors,
    const float* __restrict__ targets, const float* __restrict__ bto,
    const int* __restrict__ bti, const int* __restrict__ anyv,
    float* __restrict__ mine, unsigned* __restrict__ h1,
    double* __restrict__ pll, double* __restrict__ pllm,
    double* __restrict__ plc, int* __restrict__ pnp, int P, int G, int PT) {
  int b = blockIdx.x / PT, tile = blockIdx.x % PT;
  int tid = threadIdx.x;
  int p = tile * 256 + tid;

  __shared__ float st[128 * 15];
  __shared__ unsigned hist[1024];
  __shared__ double rs[12];
  __shared__ int ri[4];

  for (int i = tid; i < G * 15; i += 256) st[i] = targets[(size_t)b * G * 15 + i];
  for (int i = tid; i < 1024; i += 256) hist[i] = 0;
  __syncthreads();

  double ll = 0, llm = 0, lc = 0;
  int np = 0;
  if (p < P) {
    size_t idx = (size_t)b * P + p;
    int av = anyv[b];
    float ov = bto[idx];
    int ti = bti[idx];
    bool pos = av && (ov >= 0.35f);

    float2 c = ((const float2*)conf)[idx];
    float mx = fmaxf(c.x, c.y);
    float lse = mx + logf(expf(c.x - mx) + expf(c.y - mx));
    float ce = lse - (pos ? c.y : c.x);
    float mv = pos ? 0.f : ce;
    mine[idx] = mv;
    atomicAdd(&hist[__float_as_uint(mv) >> 21], 1u);

    if (pos) {
      np = 1;
      lc = (double)ce;
      float4 pr = ((const float4*)priors)[p];
      const float* t = st + ti * 15;
      float dx = 0.1f * pr.z, dy = 0.1f * pr.w;
      float gx = ((t[0] + t[2]) * 0.5f - pr.x) / dx;
      float gy = ((t[1] + t[3]) * 0.5f - pr.y) / dy;
      float gw = logf((t[2] - t[0]) / pr.z) * 5.0f;
      float gh = logf((t[3] - t[1]) / pr.w) * 5.0f;
      float4 ld = ((const float4*)loc)[idx];
      ll = (double)(sl1(ld.x - gx) + sl1(ld.y - gy) + sl1(ld.z - gw) +
                    sl1(ld.w - gh));
      const float2* lmd = (const float2*)lm + idx * 5;
      float s = 0.f;
#pragma unroll
      for (int j = 0; j < 5; ++j) {
        float2 lv = lmd[j];
        float ex = (t[4 + 2 * j] - pr.x) / dx;
        float ey = (t[5 + 2 * j] - pr.y) / dy;
        s += sl1(lv.x - ex) + sl1(lv.y - ey);
      }
      llm = (double)s;
    }
  }

  ll = dwave(ll);
  llm = dwave(llm);
  lc = dwave(lc);
#pragma unroll
  for (int o = 32; o; o >>= 1) np += __shfl_down(np, o);
  int lane = tid & 63, wid = tid >> 6;
  if (lane == 0) { rs[wid] = ll; rs[4 + wid] = llm; rs[8 + wid] = lc; ri[wid] = np; }
  __syncthreads();
  if (tid == 0) {
    pll[blockIdx.x] = rs[0] + rs[1] + rs[2] + rs[3];
    pllm[blockIdx.x] = rs[4] + rs[5] + rs[6] + rs[7];
    plc[blockIdx.x] = rs[8] + rs[9] + rs[10] + rs[11];
    pnp[blockIdx.x] = ri[0] + ri[1] + ri[2] + ri[3];
  }
  for (int i = tid; i < 1024; i += 256)
    if (hist[i]) atomicAdd(&h1[(size_t)b * 1024 + i], hist[i]);
}

__global__ __launch_bounds__(256) void k_sel1(const unsigned* __restrict__ h1,
                                              const int* __restrict__ pnp,
                                              int* __restrict__ num_pos, int P,
                                              int PT, int* __restrict__ pfx1,
                                              int* __restrict__ k1) {
  int b = blockIdx.x, tid = threadIdx.x;
  __shared__ int sn[256];
  int n = 0;
  for (int i = tid; i < PT; i += 256) n += pnp[b * PT + i];
  sn[tid] = n;
  __syncthreads();
  for (int off = 128; off; off >>= 1) {
    if (tid < off) sn[tid] += sn[tid + off];
    __syncthreads();
  }
  int npos = sn[0];
  if (tid == 0) num_pos[b] = npos;

  const unsigned* h = h1 + (size_t)b * 1024;
  __shared__ unsigned S[256];
  unsigned p0 = h[tid * 4], p1 = h[tid * 4 + 1], p2 = h[tid * 4 + 2],
           p3 = h[tid * 4 + 3];
  S[tid] = p0 + p1 + p2 + p3;
  __syncthreads();
  for (int off = 1; off < 256; off <<= 1) {
    unsigned add = (tid + off < 256) ? S[tid + off] : 0;
    __syncthreads();
    S[tid] += add;
    __syncthreads();
  }
  long long k = 7LL * (long long)npos;
  long long cap = P - 1;
  if (k > cap) k = cap;
  int cnt = __syncthreads_count(k > 0 && (long long)S[tid] >= k);
  if (cnt == 0) {
    if (tid == 0) { pfx1[b] = -1; k1[b] = 0; }
    return;
  }
  int seg = cnt - 1;
  if (tid == seg) {
    long long cum = (seg + 1 < 256) ? (long long)S[seg + 1] : 0;
    unsigned hv[4] = {p0, p1, p2, p3};
    int bin = seg * 4;
    for (int j = 3; j >= 0; --j) {
      if (cum + hv[j] >= k) { bin = seg * 4 + j; break; }
      cum += hv[j];
    }
    pfx1[b] = bin;
    k1[b] = (int)(k - cum);
  }
}

__global__ __launch_bounds__(256) void k_h2(const float* __restrict__ mine,
                                            const int* __restrict__ pfx1,
                                            unsigned* __restrict__ h2, int P,
                                            int PT4) {
  int b = blockIdx.x / PT4;
  int base = (blockIdx.x % PT4) * (256 * PPT) + threadIdx.x;
  __shared__ unsigned hist[2048];
  for (int i = threadIdx.x; i < 2048; i += 256) hist[i] = 0;
  __syncthreads();
  int pf = pfx1[b];
#pragma unroll
  for (int k = 0; k < PPT; ++k) {
    int p = base + k * 256;
    if (p < P) {
      unsigned bits = __float_as_uint(mine[(size_t)b * P + p]);
      if ((int)(bits >> 21) == pf) atomicAdd(&hist[(bits >> 10) & 2047], 1u);
    }
  }
  __syncthreads();
  for (int i = threadIdx.x; i < 2048; i += 256)
    if (hist[i]) atomicAdd(&h2[(size_t)b * 2048 + i], hist[i]);
}

__global__ __launch_bounds__(256) void k_sel2(const unsigned* __restrict__ h2,
                                              const int* __restrict__ pfx1,
                                              const int* __restrict__ k1,
                                              int* __restrict__ pfx21,
                                              int* __restrict__ k2) {
  int b = blockIdx.x, tid = threadIdx.x;
  const unsigned* h = h2 + (size_t)b * 2048;
  __shared__ unsigned S[256];
  unsigned hv[8];
  unsigned s = 0;
#pragma unroll
  for (int j = 0; j < 8; ++j) { hv[j] = h[tid * 8 + j]; s += hv[j]; }
  S[tid] = s;
  __syncthreads();
  for (int off = 1; off < 256; off <<= 1) {
    unsigned add = (tid + off < 256) ? S[tid + off] : 0;
    __syncthreads();
    S[tid] += add;
    __syncthreads();
  }
  int pf = pfx1[b];
  long long k = (long long)k1[b];
  int cnt = __syncthreads_count(pf >= 0 && (long long)S[tid] >= k);
  if (cnt == 0) {
    if (tid == 0) { pfx21[b] = -1; k2[b] = 0; }
    return;
  }
  int seg = cnt - 1;
  if (tid == seg) {
    long long cum = (seg + 1 < 256) ? (long long)S[seg + 1] : 0;
    int bin = seg * 8;
    for (int j = 7; j >= 0; --j) {
      if (cum + hv[j] >= k) { bin = seg * 8 + j; break; }
      cum += hv[j];
    }
    pfx21[b] = (pf << 11) | bin;
    k2[b] = (int)(k - cum);
  }
}

__global__ __launch_bounds__(256) void k_h3(const float* __restrict__ mine,
                                            const int* __restrict__ pfx21,
                                            unsigned* __restrict__ h3, int P,
                                            int PT4) {
  int b = blockIdx.x / PT4;
  int base = (blockIdx.x % PT4) * (256 * PPT) + threadIdx.x;
  __shared__ unsigned hist[1024];
  for (int i = threadIdx.x; i < 1024; i += 256) hist[i] = 0;
  __syncthreads();
  int pf = pfx21[b];
#pragma unroll
  for (int k = 0; k < PPT; ++k) {
    int p = base + k * 256;
    if (p < P) {
      unsigned bits = __float_as_uint(mine[(size_t)b * P + p]);
      if ((int)(bits >> 10) == pf) atomicAdd(&hist[bits & 1023], 1u);
    }
  }
  __syncthreads();
  for (int i = threadIdx.x; i < 1024; i += 256)
    if (hist[i]) atomicAdd(&h3[(size_t)b * 1024 + i], hist[i]);
}

__global__ __launch_bounds__(256) void k_sel3(const unsigned* __restrict__ h3,
                                              const int* __restrict__ pfx21,
                                              const int* __restrict__ k2,
                                              int* __restrict__ tbits,
                                              double* __restrict__ tieadd) {
  int b = blockIdx.x, tid = threadIdx.x;
  const unsigned* h = h3 + (size_t)b * 1024;
  __shared__ unsigned S[256];
  unsigned p0 = h[tid * 4], p1 = h[tid * 4 + 1], p2 = h[tid * 4 + 2],
           p3 = h[tid * 4 + 3];
  S[tid] = p0 + p1 + p2 + p3;
  __syncthreads();
  for (int off = 1; off < 256; off <<= 1) {
    unsigned add = (tid + off < 256) ? S[tid + off] : 0;
    __syncthreads();
    S[tid] += add;
    __syncthreads();
  }
  int pf = pfx21[b];
  long long k = (long long)k2[b];
  int cnt = __syncthreads_count(pf >= 0 && (long long)S[tid] >= k);
  if (cnt == 0) {
    if (tid == 0) tbits[b] = -1;
    return;
  }
  int seg = cnt - 1;
  if (tid == seg) {
    long long cum = (seg + 1 < 256) ? (long long)S[seg + 1] : 0;
    unsigned hv[4] = {p0, p1, p2, p3};
    int bin = seg * 4;
    for (int j = 3; j >= 0; --j) {
      if (cum + hv[j] >= k) { bin = seg * 4 + j; break; }
      cum += hv[j];
    }
    unsigned tb = ((unsigned)pf << 10) | (unsigned)bin;
    tbits[b] = (int)tb;
    long long nat = k - cum;
    tieadd[b] = (double)nat * (double)__uint_as_float(tb);
  }
}

__global__ __launch_bounds__(256) void k_fsum(const float* __restrict__ mine,
                                              const int* __restrict__ tbits,
                                              double* __restrict__ pfs, int P,
                                              int PT4) {
  int b = blockIdx.x / PT4;
  int base = (blockIdx.x % PT4) * (256 * PPT) + threadIdx.x;
  unsigned tb = (unsigned)tbits[b];
  double v = 0.0;
#pragma unroll
  for (int k = 0; k < PPT; ++k) {
    int p = base + k * 256;
    if (p < P) {
      unsigned bits = __float_as_uint(mine[(size_t)b * P + p]);
      if (bits > tb) v += (double)__uint_as_float(bits);
    }
  }
  v = dwave(v);
  __shared__ double rs[4];
  int lane = threadIdx.x & 63, wid = threadIdx.x >> 6;
  if (lane == 0) rs[wid] = v;
  __syncthreads();
  if (threadIdx.x == 0) pfs[blockIdx.x] = rs[0] + rs[1] + rs[2] + rs[3];
}

__global__ __launch_bounds__(256) void k_fin(
    const double* __restrict__ pll, const double* __restrict__ pllm,
    const double* __restrict__ plc, const double* __restrict__ pfs,
    const double* __restrict__ tieadd, const int* __restrict__ num_pos,
    float* __restrict__ out, int NBm, int NB4, int B) {
  int tid = threadIdx.x;
  double a = 0, c = 0, d = 0, f = 0, t = 0, n = 0;
  for (int i = tid; i < NBm; i += 256) { a += pll[i]; c += pllm[i]; d += plc[i]; }
  for (int i = tid; i < NB4; i += 256) f += pfs[i];
  for (int i = tid; i < B; i += 256) { t += tieadd[i]; n += (double)num_pos[i]; }
  a = dwave(a); c = dwave(c); d = dwave(d); f = dwave(f); t = dwave(t);
  n = dwave(n);
  __shared__ double rs[6 * 4];
  int lane = tid & 63, wid = tid >> 6;
  if (lane == 0) {
    rs[wid] = a; rs[4 + wid] = c; rs[8 + wid] = d;
    rs[12 + wid] = f; rs[16 + wid] = t; rs[20 + wid] = n;
  }
  __syncthreads();
  if (tid == 0) {
    double A = rs[0] + rs[1] + rs[2] + rs[3];
    double C = rs[4] + rs[5] + rs[6] + rs[7];
    double D = rs[8] + rs[9] + rs[10] + rs[11];
    double F = rs[12] + rs[13] + rs[14] + rs[15];
    double T = rs[16] + rs[17] + rs[18] + rs[19];
    double N = rs[20] + rs[21] + rs[22] + rs[23];
    if (N < 1.0) N = 1.0;
    out[0] = (float)(A / N);
    out[1] = (float)((D + F + T) / N);
    out[2] = (float)(C / N);
  }
}

extern "C" void kernel_launch(void* const* d_in, const int* in_sizes, int n_in,
                              void* d_out, int out_size, void* d_ws,
                              size_t ws_size, hipStream_t stream) {
  const float* loc = (const float*)d_in[0];
  const float* conf = (const float*)d_in[1];
  const float* lm = (const float*)d_in[2];
  const float* priors = (const float*)d_in[3];
  const float* targets = (const float*)d_in[4];

  int P = in_sizes[3] / 4;
  int B = in_sizes[0] / (4 * P);
  int G = in_sizes[4] / (15 * B);
  int PT = (P + 255) / 256;
  int PT2 = (P + 256 * PPI - 1) / (256 * PPI);
  int PT4 = (P + 256 * PPT - 1) / (256 * PPT);
  int NBm = B * PT;
  int NB4 = B * PT4;
  int NGC = (G + GC - 1) / GC;
  int PC = 8;
  int NIOU = B * PT2;
  int NBP = B * NGC * PC;

  char* w = (char*)d_ws;
  size_t off = 0;
  // ---- zeroed region ----
  unsigned long long* bp = (unsigned long long*)(w + off);
  off += (size_t)B * G * 8;
  double* tieadd = (double*)(w + off);
  off += (size_t)B * 8;
  int* ctrl = (int*)(w + off);
  off += (size_t)(8 * B) * 4;
  int* anyv = ctrl;
  int* num_pos = ctrl + B;
  int* pfx1 = ctrl + 2 * B;
  int* k1 = ctrl + 3 * B;
  int* pfx21 = ctrl + 4 * B;
  int* k2 = ctrl + 5 * B;
  int* tbits = ctrl + 6 * B;
  unsigned* h1 = (unsigned*)(w + off);
  off += (size_t)B * 1024 * 4;
  unsigned* h2 = (unsigned*)(w + off);
  off += (size_t)B * 2048 * 4;
  unsigned* h3 = (unsigned*)(w + off);
  off += (size_t)B * 1024 * 4;
  size_t clear_bytes = off;
  // ---- non-zeroed region ----
  off = (off + 255) & ~(size_t)255;
  float* bto = (float*)(w + off);
  off += (size_t)B * P * 4;
  int* bti = (int*)(w + off);
  off += (size_t)B * P * 4;
  float* mine = (float*)(w + off);
  off += (size_t)B * P * 4;
  double* pll = (double*)(w + off);
  off += (size_t)NBm * 8;
  double* pllm = (double*)(w + off);
  off += (size_t)NBm * 8;
  double* plc = (double*)(w + off);
  off += (size_t)NBm * 8;
  double* pfs = (double*)(w + off);
  off += (size_t)NB4 * 8;
  int* pnp = (int*)(w + off);
  off += (size_t)NBm * 4;

  hipMemsetAsync(d_ws, 0, clear_bytes, stream);

  k_match<<<NIOU + NBP, 256, 0, stream>>>(priors, targets, bto, bti, bp, P, G,
                                          NIOU, PT2, NGC, PC);
  k_scatter<<<B, G, 0, stream>>>(bp, bto, bti, anyv, P, G);
  k_main<<<B * PT, 256, 0, stream>>>(loc, conf, lm, priors, targets, bto, bti,
                                     anyv, mine, h1, pll, pllm, plc, pnp, P, G,
                                     PT);
  k_sel1<<<B, 256, 0, stream>>>(h1, pnp, num_pos, P, PT, pfx1, k1);
  k_h2<<<B * PT4, 256, 0, stream>>>(mine, pfx1, h2, P, PT4);
  k_sel2<<<B, 256, 0, stream>>>(h2, pfx1, k1, pfx21, k2);
  k_h3<<<B * PT4, 256, 0, stream>>>(mine, pfx21, h3, P, PT4);
  k_sel3<<<B, 256, 0, stream>>>(h3, pfx21, k2, tbits, tieadd);
  k_fsum<<<B * PT4, 256, 0, stream>>>(mine, tbits, pfs, P, PT4);
  k_fin<<<1, 256, 0, stream>>>(pll, pllm, plc, pfs, tieadd, num_pos,
                               (float*)d_out, NBm, NB4, B);
}

// Round 8
// 197.821 us; speedup vs baseline: 2.7820x; 1.1187x over previous
//
#include <hip/hip_runtime.h>
#include <stdint.h>

// MultiBoxLoss B=16, P=43008, G=128.
// R8: k_match -> plain scalar math (R7's v2f cost +25% inst in packing movs),
//     2x unrolled inner loops (2 loads in flight, more indep chains).
//     Hard-negative fast path: when k == P-1 (7*num_pos >= P-1, the common
//     case), selected negs = all negs and loss_c_neg = sum(mine); k_sel1 sets
//     tbits=0 & pfx1=-2, h2/sel2/h3/sel3 early-exit. General radix kept.

#define GC 8    // GTs per bp-role block
#define PPT 4   // priors/thread in tail scan kernels
#define PPI 2   // priors/thread in iou role

__device__ __forceinline__ float sl1(float x) {
  float a = fabsf(x);
  return a < 1.f ? 0.5f * a * a : a - 0.5f;
}

__device__ __forceinline__ double dwave(double v) {
#pragma unroll
  for (int o = 32; o; o >>= 1) v += __shfl_down(v, o);
  return v;
}

__global__ __launch_bounds__(256) void k_match(
    const float* __restrict__ priors, const float* __restrict__ targets,
    float* __restrict__ bto, int* __restrict__ bti,
    unsigned long long* __restrict__ bp, int P, int G, int NIOU, int PT2,
    int NGC, int PC) {
  int tid = threadIdx.x;
  __shared__ float4 sgt[128];
  __shared__ unsigned long long sred[GC * 256];  // 16 KB (bp role)

  if ((int)blockIdx.x < NIOU) {
    // ---- iou role: per-prior best-truth over all g ----
    int b = blockIdx.x / PT2, tile = blockIdx.x % PT2;
    int base = tile * (256 * PPI);
    for (int g = tid; g < G; g += 256) {
      const float* t = targets + ((size_t)b * G + g) * 15;
      sgt[g] = make_float4(t[0], t[1], t[2], t[3]);
    }
    __syncthreads();

    float px1[PPI], py1[PPI], px2[PPI], py2[PPI], pa[PPI];
    float bi[PPI], bu[PPI];
    int bidx[PPI];
#pragma unroll
    for (int k = 0; k < PPI; ++k) {
      int p = base + tid + k * 256;
      int pl = p < P ? p : P - 1;
      float4 pr = ((const float4*)priors)[pl];
      px1[k] = pr.x - pr.z * 0.5f; py1[k] = pr.y - pr.w * 0.5f;
      px2[k] = pr.x + pr.z * 0.5f; py2[k] = pr.y + pr.w * 0.5f;
      pa[k] = pr.z * pr.w;
      bi[k] = -1.f; bu[k] = 1.f; bidx[k] = 0;
    }

    for (int g = 0; g < G; g += 2) {
      float4 T0 = sgt[g];
      float4 T1 = sgt[g + 1];
      float A0 = (T0.z - T0.x) * (T0.w - T0.y);
      float A1 = (T1.z - T1.x) * (T1.w - T1.y);
#pragma unroll
      for (int k = 0; k < PPI; ++k) {
        {
          float iw = fminf(T0.z, px2[k]) - fmaxf(T0.x, px1[k]);
          float ih = fminf(T0.w, py2[k]) - fmaxf(T0.y, py1[k]);
          iw = fmaxf(iw, 0.f); ih = fmaxf(ih, 0.f);
          float inter = iw * ih;
          float uni = (A0 + pa[k]) - inter;
          if (inter * bu[k] > bi[k] * uni) { bi[k] = inter; bu[k] = uni; bidx[k] = g; }
        }
        {
          float iw = fminf(T1.z, px2[k]) - fmaxf(T1.x, px1[k]);
          float ih = fminf(T1.w, py2[k]) - fmaxf(T1.y, py1[k]);
          iw = fmaxf(iw, 0.f); ih = fmaxf(ih, 0.f);
          float inter = iw * ih;
          float uni = (A1 + pa[k]) - inter;
          if (inter * bu[k] > bi[k] * uni) { bi[k] = inter; bu[k] = uni; bidx[k] = g + 1; }
        }
      }
    }
#pragma unroll
    for (int k = 0; k < PPI; ++k) {
      int p = base + tid + k * 256;
      if (p < P) {
        bto[(size_t)b * P + p] = bi[k] / bu[k];
        bti[(size_t)b * P + p] = bidx[k];
      }
    }
  } else {
    // ---- bp role: per-GT best-prior over a P-chunk ----
    int bc = blockIdx.x - NIOU;
    int pc = bc % PC;
    int gcb = (bc / PC) % NGC;
    int b = bc / (PC * NGC);
    int g0 = gcb * GC;

    if (tid < GC) {
      int g = g0 + tid;
      float4 v = make_float4(0.f, 0.f, 0.f, 0.f);
      if (g < G) {
        const float* t = targets + ((size_t)b * G + g) * 15;
        v = make_float4(t[0], t[1], t[2], t[3]);
      }
      sgt[tid] = v;
    }
    __syncthreads();

    float gx1[GC], gy1[GC], gx2[GC], gy2[GC], ga[GC];
#pragma unroll
    for (int j = 0; j < GC; ++j) {
      float4 T = sgt[j];
      gx1[j] = T.x; gy1[j] = T.y; gx2[j] = T.z; gy2[j] = T.w;
      ga[j] = (T.z - T.x) * (T.w - T.y);
    }

    int chunk = (P + PC - 1) / PC;
    int ps = pc * chunk;
    int pe = ps + chunk; if (pe > P) pe = P;
    int count = pe - ps;

    // zero-iou fallback candidate = first visited prior (exact argmax-first)
    float bi[GC], bu[GC];
    unsigned bpp[GC];
#pragma unroll
    for (int j = 0; j < GC; ++j) { bi[j] = 0.f; bu[j] = 1.f; bpp[j] = (unsigned)(ps + tid); }

    for (int i = tid; i < count; i += 512) {
      int p0 = ps + i;
      int i1 = i + 256;
      int p1 = (i1 < count) ? ps + i1 : p0;  // clamped duplicate: strict > => no-op
      float4 q0 = ((const float4*)priors)[p0];
      float4 q1 = ((const float4*)priors)[p1];
      float ax1 = q0.x - q0.z * 0.5f, ay1 = q0.y - q0.w * 0.5f;
      float ax2 = q0.x + q0.z * 0.5f, ay2 = q0.y + q0.w * 0.5f;
      float aa = q0.z * q0.w;
      float bx1 = q1.x - q1.z * 0.5f, by1 = q1.y - q1.w * 0.5f;
      float bx2 = q1.x + q1.z * 0.5f, by2 = q1.y + q1.w * 0.5f;
      float ba = q1.z * q1.w;
#pragma unroll
      for (int j = 0; j < GC; ++j) {
        {
          float iw = fminf(gx2[j], ax2) - fmaxf(gx1[j], ax1);
          float ih = fminf(gy2[j], ay2) - fmaxf(gy1[j], ay1);
          iw = fmaxf(iw, 0.f); ih = fmaxf(ih, 0.f);
          float inter = iw * ih;
          float uni = (ga[j] + aa) - inter;
          if (inter * bu[j] > bi[j] * uni) { bi[j] = inter; bu[j] = uni; bpp[j] = (unsigned)p0; }
        }
        {
          float iw = fminf(gx2[j], bx2) - fmaxf(gx1[j], bx1);
          float ih = fminf(gy2[j], by2) - fmaxf(gy1[j], by1);
          iw = fmaxf(iw, 0.f); ih = fmaxf(ih, 0.f);
          float inter = iw * ih;
          float uni = (ga[j] + ba) - inter;
          if (inter * bu[j] > bi[j] * uni) { bi[j] = inter; bu[j] = uni; bpp[j] = (unsigned)p1; }
        }
      }
    }

    // divide early -> packed u64 (iou bits | ~p), LDS max tree
#pragma unroll
    for (int j = 0; j < GC; ++j) {
      float iou = bi[j] / bu[j];
      unsigned long long pk =
          ((unsigned long long)__float_as_uint(iou) << 32) | (unsigned)(~bpp[j]);
      sred[j * 256 + tid] = pk;
    }
    __syncthreads();
    {
      int j = tid >> 5, s = tid & 31;
      unsigned long long m = sred[j * 256 + s];
#pragma unroll
      for (int t = 1; t < 8; ++t) {
        unsigned long long v = sred[j * 256 + s + t * 32];
        if (v > m) m = v;
      }
      __syncthreads();
      sred[j * 256 + s] = m;
    }
    __syncthreads();
    if (tid < GC) {
      unsigned long long m = sred[tid * 256];
      for (int s = 1; s < 32; ++s) {
        unsigned long long v = sred[tid * 256 + s];
        if (v > m) m = v;
      }
      int g = g0 + tid;
      if (g < G) atomicMax(&bp[(size_t)b * G + g], m);
    }
  }
}

__global__ void k_scatter(const unsigned long long* __restrict__ bp,
                          float* __restrict__ bto, int* __restrict__ bti,
                          int* __restrict__ anyv, int P, int G) {
  int b = blockIdx.x, g = threadIdx.x;
  __shared__ unsigned spp[128];
  __shared__ int s_any;
  if (g == 0) s_any = 0;
  __syncthreads();
  unsigned long long m = bp[(size_t)b * G + g];
  unsigned pp = ~(unsigned)m;
  float val = __uint_as_float((unsigned)(m >> 32));
  bool ok = (m != 0ULL);
  float oldv = 0.f;
  if (ok) oldv = bto[(size_t)b * P + pp];
  spp[g] = ok ? pp : 0xFFFFFFFFu;
  if (ok && val >= 0.2f) s_any = 1;
  __syncthreads();
  bool win = ok;
  for (int g2 = g + 1; g2 < G; ++g2)
    if (spp[g2] == pp) win = false;
  if (win) {
    bto[(size_t)b * P + pp] = (val >= 0.2f) ? 2.0f : oldv;
    bti[(size_t)b * P + pp] = g;
  }
  __syncthreads();
  if (g == 0) anyv[b] = s_any;
}

__global__ __launch_bounds__(256) void k_main(
    const float* __restrict__ loc, const float* __restrict__ conf,
    const float* __restrict__ lm, const float* __restrict__ priors,
    const float* __restrict__ targets, const float* __restrict__ bto,
    const int* __restrict__ bti, const int* __restrict__ anyv,
    float* __restrict__ mine, unsigned* __restrict__ h1,
    double* __restrict__ pll, double* __restrict__ pllm,
    double* __restrict__ plc, int* __restrict__ pnp, int P, int G, int PT) {
  int b = blockIdx.x / PT, tile = blockIdx.x % PT;
  int tid = threadIdx.x;
  int p = tile * 256 + tid;

  __shared__ float st[128 * 15];
  __shared__ unsigned hist[1024];
  __shared__ double rs[12];
  __shared__ int ri[4];

  for (int i = tid; i < G * 15; i += 256) st[i] = targets[(size_t)b * G * 15 + i];
  for (int i = tid; i < 1024; i += 256) hist[i] = 0;
  __syncthreads();

  double ll = 0, llm = 0, lc = 0;
  int np = 0;
  if (p < P) {
    size_t idx = (size_t)b * P + p;
    int av = anyv[b];
    float ov = bto[idx];
    int ti = bti[idx];
    bool pos = av && (ov >= 0.35f);

    float2 c = ((const float2*)conf)[idx];
    float mx = fmaxf(c.x, c.y);
    float lse = mx + logf(expf(c.x - mx) + expf(c.y - mx));
    float ce = lse - (pos ? c.y : c.x);
    float mv = pos ? 0.f : ce;
    mine[idx] = mv;
    atomicAdd(&hist[__float_as_uint(mv) >> 21], 1u);

    if (pos) {
      np = 1;
      lc = (double)ce;
      float4 pr = ((const float4*)priors)[p];
      const float* t = st + ti * 15;
      float dx = 0.1f * pr.z, dy = 0.1f * pr.w;
      float gx = ((t[0] + t[2]) * 0.5f - pr.x) / dx;
      float gy = ((t[1] + t[3]) * 0.5f - pr.y) / dy;
      float gw = logf((t[2] - t[0]) / pr.z) * 5.0f;
      float gh = logf((t[3] - t[1]) / pr.w) * 5.0f;
      float4 ld = ((const float4*)loc)[idx];
      ll = (double)(sl1(ld.x - gx) + sl1(ld.y - gy) + sl1(ld.z - gw) +
                    sl1(ld.w - gh));
      const float2* lmd = (const float2*)lm + idx * 5;
      float s = 0.f;
#pragma unroll
      for (int j = 0; j < 5; ++j) {
        float2 lv = lmd[j];
        float ex = (t[4 + 2 * j] - pr.x) / dx;
        float ey = (t[5 + 2 * j] - pr.y) / dy;
        s += sl1(lv.x - ex) + sl1(lv.y - ey);
      }
      llm = (double)s;
    }
  }

  ll = dwave(ll);
  llm = dwave(llm);
  lc = dwave(lc);
#pragma unroll
  for (int o = 32; o; o >>= 1) np += __shfl_down(np, o);
  int lane = tid & 63, wid = tid >> 6;
  if (lane == 0) { rs[wid] = ll; rs[4 + wid] = llm; rs[8 + wid] = lc; ri[wid] = np; }
  __syncthreads();
  if (tid == 0) {
    pll[blockIdx.x] = rs[0] + rs[1] + rs[2] + rs[3];
    pllm[blockIdx.x] = rs[4] + rs[5] + rs[6] + rs[7];
    plc[blockIdx.x] = rs[8] + rs[9] + rs[10] + rs[11];
    pnp[blockIdx.x] = ri[0] + ri[1] + ri[2] + ri[3];
  }
  for (int i = tid; i < 1024; i += 256)
    if (hist[i]) atomicAdd(&h1[(size_t)b * 1024 + i], hist[i]);
}

__global__ __launch_bounds__(256) void k_sel1(const unsigned* __restrict__ h1,
                                              const int* __restrict__ pnp,
                                              int* __restrict__ num_pos, int P,
                                              int PT, int* __restrict__ pfx1,
                                              int* __restrict__ k1,
                                              int* __restrict__ tbits) {
  int b = blockIdx.x, tid = threadIdx.x;
  __shared__ int sn[256];
  int n = 0;
  for (int i = tid; i < PT; i += 256) n += pnp[b * PT + i];
  sn[tid] = n;
  __syncthreads();
  for (int off = 128; off; off >>= 1) {
    if (tid < off) sn[tid] += sn[tid + off];
    __syncthreads();
  }
  int npos = sn[0];
  if (tid == 0) num_pos[b] = npos;

  long long k = 7LL * (long long)npos;
  long long cap = P - 1;
  if (k <= 0) {
    if (tid == 0) { pfx1[b] = -1; k1[b] = 0; }
    return;
  }
  if (k >= cap) {
    // FAST PATH: every negative selected; loss_c_neg = sum(mine).
    // tbits=0 -> k_fsum sums all bits>0 (mine>=0, zeros contribute 0).
    if (tid == 0) { pfx1[b] = -2; k1[b] = 0; tbits[b] = 0; }
    return;
  }

  const unsigned* h = h1 + (size_t)b * 1024;
  __shared__ unsigned S[256];
  unsigned p0 = h[tid * 4], p1 = h[tid * 4 + 1], p2 = h[tid * 4 + 2],
           p3 = h[tid * 4 + 3];
  S[tid] = p0 + p1 + p2 + p3;
  __syncthreads();
  for (int off = 1; off < 256; off <<= 1) {
    unsigned add = (tid + off < 256) ? S[tid + off] : 0;
    __syncthreads();
    S[tid] += add;
    __syncthreads();
  }
  int cnt = __syncthreads_count((long long)S[tid] >= k);
  if (cnt == 0) {
    if (tid == 0) { pfx1[b] = -1; k1[b] = 0; }
    return;
  }
  int seg = cnt - 1;
  if (tid == seg) {
    long long cum = (seg + 1 < 256) ? (long long)S[seg + 1] : 0;
    unsigned hv[4] = {p0, p1, p2, p3};
    int bin = seg * 4;
    for (int j = 3; j >= 0; --j) {
      if (cum + hv[j] >= k) { bin = seg * 4 + j; break; }
      cum += hv[j];
    }
    pfx1[b] = bin;
    k1[b] = (int)(k - cum);
  }
}

__global__ __launch_bounds__(256) void k_h2(const float* __restrict__ mine,
                                            const int* __restrict__ pfx1,
                                            unsigned* __restrict__ h2, int P,
                                            int PT4) {
  int b = blockIdx.x / PT4;
  int pf = pfx1[b];
  if (pf < 0) return;  // fast path / none
  int base = (blockIdx.x % PT4) * (256 * PPT) + threadIdx.x;
  __shared__ unsigned hist[2048];
  for (int i = threadIdx.x; i < 2048; i += 256) hist[i] = 0;
  __syncthreads();
#pragma unroll
  for (int k = 0; k < PPT; ++k) {
    int p = base + k * 256;
    if (p < P) {
      unsigned bits = __float_as_uint(mine[(size_t)b * P + p]);
      if ((int)(bits >> 21) == pf) atomicAdd(&hist[(bits >> 10) & 2047], 1u);
    }
  }
  __syncthreads();
  for (int i = threadIdx.x; i < 2048; i += 256)
    if (hist[i]) atomicAdd(&h2[(size_t)b * 2048 + i], hist[i]);
}

__global__ __launch_bounds__(256) void k_sel2(const unsigned* __restrict__ h2,
                                              const int* __restrict__ pfx1,
                                              const int* __restrict__ k1,
                                              int* __restrict__ pfx21,
                                              int* __restrict__ k2) {
  int b = blockIdx.x, tid = threadIdx.x;
  int pf = pfx1[b];
  if (pf < 0) {
    if (tid == 0) { pfx21[b] = pf; k2[b] = 0; }  // propagate -1/-2 marker
    return;
  }
  const unsigned* h = h2 + (size_t)b * 2048;
  __shared__ unsigned S[256];
  unsigned hv[8];
  unsigned s = 0;
#pragma unroll
  for (int j = 0; j < 8; ++j) { hv[j] = h[tid * 8 + j]; s += hv[j]; }
  S[tid] = s;
  __syncthreads();
  for (int off = 1; off < 256; off <<= 1) {
    unsigned add = (tid + off < 256) ? S[tid + off] : 0;
    __syncthreads();
    S[tid] += add;
    __syncthreads();
  }
  long long k = (long long)k1[b];
  int cnt = __syncthreads_count((long long)S[tid] >= k);
  if (cnt == 0) {
    if (tid == 0) { pfx21[b] = -1; k2[b] = 0; }
    return;
  }
  int seg = cnt - 1;
  if (tid == seg) {
    long long cum = (seg + 1 < 256) ? (long long)S[seg + 1] : 0;
    int bin = seg * 8;
    for (int j = 7; j >= 0; --j) {
      if (cum + hv[j] >= k) { bin = seg * 8 + j; break; }
      cum += hv[j];
    }
    pfx21[b] = (pf << 11) | bin;
    k2[b] = (int)(k - cum);
  }
}

__global__ __launch_bounds__(256) void k_h3(const float* __restrict__ mine,
                                            const int* __restrict__ pfx21,
                                            unsigned* __restrict__ h3, int P,
                                            int PT4) {
  int b = blockIdx.x / PT4;
  int pf = pfx21[b];
  if (pf < 0) return;
  int base = (blockIdx.x % PT4) * (256 * PPT) + threadIdx.x;
  __shared__ unsigned hist[1024];
  for (int i = threadIdx.x; i < 1024; i += 256) hist[i] = 0;
  __syncthreads();
#pragma unroll
  for (int k = 0; k < PPT; ++k) {
    int p = base + k * 256;
    if (p < P) {
      unsigned bits = __float_as_uint(mine[(size_t)b * P + p]);
      if ((int)(bits >> 10) == pf) atomicAdd(&hist[bits & 1023], 1u);
    }
  }
  __syncthreads();
  for (int i = threadIdx.x; i < 1024; i += 256)
    if (hist[i]) atomicAdd(&h3[(size_t)b * 1024 + i], hist[i]);
}

__global__ __launch_bounds__(256) void k_sel3(const unsigned* __restrict__ h3,
                                              const int* __restrict__ pfx21,
                                              const int* __restrict__ k2,
                                              int* __restrict__ tbits,
                                              double* __restrict__ tieadd) {
  int b = blockIdx.x, tid = threadIdx.x;
  int pf = pfx21[b];
  if (pf == -2) return;  // fast path: tbits already 0 from k_sel1
  if (pf == -1) {
    if (tid == 0) tbits[b] = -1;  // nothing selected
    return;
  }
  const unsigned* h = h3 + (size_t)b * 1024;
  __shared__ unsigned S[256];
  unsigned p0 = h[tid * 4], p1 = h[tid * 4 + 1], p2 = h[tid * 4 + 2],
           p3 = h[tid * 4 + 3];
  S[tid] = p0 + p1 + p2 + p3;
  __syncthreads();
  for (int off = 1; off < 256; off <<= 1) {
    unsigned add = (tid + off < 256) ? S[tid + off] : 0;
    __syncthreads();
    S[tid] += add;
    __syncthreads();
  }
  long long k = (long long)k2[b];
  int cnt = __syncthreads_count((long long)S[tid] >= k);
  if (cnt == 0) {
    if (tid == 0) tbits[b] = -1;
    return;
  }
  int seg = cnt - 1;
  if (tid == seg) {
    long long cum = (seg + 1 < 256) ? (long long)S[seg + 1] : 0;
    unsigned hv[4] = {p0, p1, p2, p3};
    int bin = seg * 4;
    for (int j = 3; j >= 0; --j) {
      if (cum + hv[j] >= k) { bin = seg * 4 + j; break; }
      cum += hv[j];
    }
    unsigned tb = ((unsigned)pf << 10) | (unsigned)bin;
    tbits[b] = (int)tb;
    long long nat = k - cum;
    tieadd[b] = (double)nat * (double)__uint_as_float(tb);
  }
}

__global__ __launch_bounds__(256) void k_fsum(const float* __restrict__ mine,
                                              const int* __restrict__ tbits,
                                              double* __restrict__ pfs, int P,
                                              int PT4) {
  int b = blockIdx.x / PT4;
  int base = (blockIdx.x % PT4) * (256 * PPT) + threadIdx.x;
  unsigned tb = (unsigned)tbits[b];
  double v = 0.0;
#pragma unroll
  for (int k = 0; k < PPT; ++k) {
    int p = base + k * 256;
    if (p < P) {
      unsigned bits = __float_as_uint(mine[(size_t)b * P + p]);
      if (bits > tb) v += (double)__uint_as_float(bits);
    }
  }
  v = dwave(v);
  __shared__ double rs[4];
  int lane = threadIdx.x & 63, wid = threadIdx.x >> 6;
  if (lane == 0) rs[wid] = v;
  __syncthreads();
  if (threadIdx.x == 0) pfs[blockIdx.x] = rs[0] + rs[1] + rs[2] + rs[3];
}

__global__ __launch_bounds__(256) void k_fin(
    const double* __restrict__ pll, const double* __restrict__ pllm,
    const double* __restrict__ plc, const double* __restrict__ pfs,
    const double* __restrict__ tieadd, const int* __restrict__ num_pos,
    float* __restrict__ out, int NBm, int NB4, int B) {
  int tid = threadIdx.x;
  double a = 0, c = 0, d = 0, f = 0, t = 0, n = 0;
  for (int i = tid; i < NBm; i += 256) { a += pll[i]; c += pllm[i]; d += plc[i]; }
  for (int i = tid; i < NB4; i += 256) f += pfs[i];
  for (int i = tid; i < B; i += 256) { t += tieadd[i]; n += (double)num_pos[i]; }
  a = dwave(a); c = dwave(c); d = dwave(d); f = dwave(f); t = dwave(t);
  n = dwave(n);
  __shared__ double rs[6 * 4];
  int lane = tid & 63, wid = tid >> 6;
  if (lane == 0) {
    rs[wid] = a; rs[4 + wid] = c; rs[8 + wid] = d;
    rs[12 + wid] = f; rs[16 + wid] = t; rs[20 + wid] = n;
  }
  __syncthreads();
  if (tid == 0) {
    double A = rs[0] + rs[1] + rs[2] + rs[3];
    double C = rs[4] + rs[5] + rs[6] + rs[7];
    double D = rs[8] + rs[9] + rs[10] + rs[11];
    double F = rs[12] + rs[13] + rs[14] + rs[15];
    double T = rs[16] + rs[17] + rs[18] + rs[19];
    double N = rs[20] + rs[21] + rs[22] + rs[23];
    if (N < 1.0) N = 1.0;
    out[0] = (float)(A / N);
    out[1] = (float)((D + F + T) / N);
    out[2] = (float)(C / N);
  }
}

extern "C" void kernel_launch(void* const* d_in, const int* in_sizes, int n_in,
                              void* d_out, int out_size, void* d_ws,
                              size_t ws_size, hipStream_t stream) {
  const float* loc = (const float*)d_in[0];
  const float* conf = (const float*)d_in[1];
  const float* lm = (const float*)d_in[2];
  const float* priors = (const float*)d_in[3];
  const float* targets = (const float*)d_in[4];

  int P = in_sizes[3] / 4;
  int B = in_sizes[0] / (4 * P);
  int G = in_sizes[4] / (15 * B);
  int PT = (P + 255) / 256;
  int PT2 = (P + 256 * PPI - 1) / (256 * PPI);
  int PT4 = (P + 256 * PPT - 1) / (256 * PPT);
  int NBm = B * PT;
  int NB4 = B * PT4;
  int NGC = (G + GC - 1) / GC;
  int PC = 8;
  int NIOU = B * PT2;
  int NBP = B * NGC * PC;

  char* w = (char*)d_ws;
  size_t off = 0;
  // ---- zeroed region ----
  unsigned long long* bp = (unsigned long long*)(w + off);
  off += (size_t)B * G * 8;
  double* tieadd = (double*)(w + off);
  off += (size_t)B * 8;
  int* ctrl = (int*)(w + off);
  off += (size_t)(8 * B) * 4;
  int* anyv = ctrl;
  int* num_pos = ctrl + B;
  int* pfx1 = ctrl + 2 * B;
  int* k1 = ctrl + 3 * B;
  int* pfx21 = ctrl + 4 * B;
  int* k2 = ctrl + 5 * B;
  int* tbits = ctrl + 6 * B;
  unsigned* h1 = (unsigned*)(w + off);
  off += (size_t)B * 1024 * 4;
  unsigned* h2 = (unsigned*)(w + off);
  off += (size_t)B * 2048 * 4;
  unsigned* h3 = (unsigned*)(w + off);
  off += (size_t)B * 1024 * 4;
  size_t clear_bytes = off;
  // ---- non-zeroed region ----
  off = (off + 255) & ~(size_t)255;
  float* bto = (float*)(w + off);
  off += (size_t)B * P * 4;
  int* bti = (int*)(w + off);
  off += (size_t)B * P * 4;
  float* mine = (float*)(w + off);
  off += (size_t)B * P * 4;
  double* pll = (double*)(w + off);
  off += (size_t)NBm * 8;
  double* pllm = (double*)(w + off);
  off += (size_t)NBm * 8;
  double* plc = (double*)(w + off);
  off += (size_t)NBm * 8;
  double* pfs = (double*)(w + off);
  off += (size_t)NB4 * 8;
  int* pnp = (int*)(w + off);
  off += (size_t)NBm * 4;

  hipMemsetAsync(d_ws, 0, clear_bytes, stream);

  k_match<<<NIOU + NBP, 256, 0, stream>>>(priors, targets, bto, bti, bp, P, G,
                                          NIOU, PT2, NGC, PC);
  k_scatter<<<B, G, 0, stream>>>(bp, bto, bti, anyv, P, G);
  k_main<<<B * PT, 256, 0, stream>>>(loc, conf, lm, priors, targets, bto, bti,
                                     anyv, mine, h1, pll, pllm, plc, pnp, P, G,
                                     PT);
  k_sel1<<<B, 256, 0, stream>>>(h1, pnp, num_pos, P, PT, pfx1, k1, tbits);
  k_h2<<<B * PT4, 256, 0, stream>>>(mine, pfx1, h2, P, PT4);
  k_sel2<<<B, 256, 0, stream>>>(h2, pfx1, k1, pfx21, k2);
  k_h3<<<B * PT4, 256, 0, stream>>>(mine, pfx21, h3, P, PT4);
  k_sel3<<<B, 256, 0, stream>>>(h3, pfx21, k2, tbits, tieadd);
  k_fsum<<<B * PT4, 256, 0, stream>>>(mine, tbits, pfs, P, PT4);
  k_fin<<<1, 256, 0, stream>>>(pll, pllm, plc, pfs, tieadd, num_pos,
                               (float*)d_out, NBm, NB4, B);
}

// Round 9
// 182.380 us; speedup vs baseline: 3.0175x; 1.0847x over previous
//
#include <hip/hip_runtime.h>
#include <stdint.h>

// MultiBoxLoss B=16, P=43008, G=128.
// R9: S-trick in both match roles: track (bi=inter, sb=A+pa of best); compare
//     inter*sb > bi*S (algebraically == rational compare, uni>0 always).
//     iou role PPI=3 + LDS area array. Tail: h2/sel2/h3/sel3/fsum merged into
//     one per-b k_select (in-LDS radix, early-exit on fast path); k_main
//     always accumulates sum(mine) partials so fast path needs no extra pass.
//     6 kernels + memset.

#define GC 8    // GTs per bp-role block
#define PPI 3   // priors/thread in iou role

__device__ __forceinline__ float sl1(float x) {
  float a = fabsf(x);
  return a < 1.f ? 0.5f * a * a : a - 0.5f;
}

__device__ __forceinline__ double dwave(double v) {
#pragma unroll
  for (int o = 32; o; o >>= 1) v += __shfl_down(v, o);
  return v;
}

__global__ __launch_bounds__(256) void k_match(
    const float* __restrict__ priors, const float* __restrict__ targets,
    float* __restrict__ bto, int* __restrict__ bti,
    unsigned long long* __restrict__ bp, int P, int G, int NIOU, int PT3,
    int NGC, int PC) {
  int tid = threadIdx.x;
  __shared__ float4 sgt[128];
  __shared__ float sga[128];
  __shared__ unsigned long long sred[GC * 256];  // 16 KB (bp role)

  if ((int)blockIdx.x < NIOU) {
    // ---- iou role: per-prior best-truth over all g ----
    int b = blockIdx.x / PT3, tile = blockIdx.x % PT3;
    int base = tile * (256 * PPI);
    for (int g = tid; g < G; g += 256) {
      const float* t = targets + ((size_t)b * G + g) * 15;
      float x1 = t[0], y1 = t[1], x2 = t[2], y2 = t[3];
      sgt[g] = make_float4(x1, y1, x2, y2);
      sga[g] = (x2 - x1) * (y2 - y1);
    }
    __syncthreads();

    float px1[PPI], py1[PPI], px2[PPI], py2[PPI], pa[PPI];
    float bi[PPI], sb[PPI];
    int bidx[PPI];
#pragma unroll
    for (int k = 0; k < PPI; ++k) {
      int p = base + tid + k * 256;
      int pl = p < P ? p : P - 1;
      float4 pr = ((const float4*)priors)[pl];
      px1[k] = pr.x - pr.z * 0.5f; py1[k] = pr.y - pr.w * 0.5f;
      px2[k] = pr.x + pr.z * 0.5f; py2[k] = pr.y + pr.w * 0.5f;
      pa[k] = pr.z * pr.w;
      bi[k] = 0.f; sb[k] = 1.f; bidx[k] = 0;
    }

    for (int g = 0; g < G; g += 2) {
      float4 T0 = sgt[g];
      float4 T1 = sgt[g + 1];
      float A0 = sga[g];
      float A1 = sga[g + 1];
#pragma unroll
      for (int k = 0; k < PPI; ++k) {
        {
          float iw = fminf(T0.z, px2[k]) - fmaxf(T0.x, px1[k]);
          float ih = fminf(T0.w, py2[k]) - fmaxf(T0.y, py1[k]);
          float inter = fmaxf(iw, 0.f) * fmaxf(ih, 0.f);
          float S = A0 + pa[k];
          if (inter * sb[k] > bi[k] * S) { bi[k] = inter; sb[k] = S; bidx[k] = g; }
        }
        {
          float iw = fminf(T1.z, px2[k]) - fmaxf(T1.x, px1[k]);
          float ih = fminf(T1.w, py2[k]) - fmaxf(T1.y, py1[k]);
          float inter = fmaxf(iw, 0.f) * fmaxf(ih, 0.f);
          float S = A1 + pa[k];
          if (inter * sb[k] > bi[k] * S) { bi[k] = inter; sb[k] = S; bidx[k] = g + 1; }
        }
      }
    }
#pragma unroll
    for (int k = 0; k < PPI; ++k) {
      int p = base + tid + k * 256;
      if (p < P) {
        bto[(size_t)b * P + p] = bi[k] / (sb[k] - bi[k]);  // uni = S_b - inter_b
        bti[(size_t)b * P + p] = bidx[k];
      }
    }
  } else {
    // ---- bp role: per-GT best-prior over a P-chunk ----
    int bc = blockIdx.x - NIOU;
    int pc = bc % PC;
    int gcb = (bc / PC) % NGC;
    int b = bc / (PC * NGC);
    int g0 = gcb * GC;

    if (tid < GC) {
      int g = g0 + tid;
      float4 v = make_float4(0.f, 0.f, 0.f, 0.f);
      if (g < G) {
        const float* t = targets + ((size_t)b * G + g) * 15;
        v = make_float4(t[0], t[1], t[2], t[3]);
      }
      sgt[tid] = v;
    }
    __syncthreads();

    float gx1[GC], gy1[GC], gx2[GC], gy2[GC], ga[GC];
#pragma unroll
    for (int j = 0; j < GC; ++j) {
      float4 T = sgt[j];
      gx1[j] = T.x; gy1[j] = T.y; gx2[j] = T.z; gy2[j] = T.w;
      ga[j] = (T.z - T.x) * (T.w - T.y);
    }

    int chunk = (P + PC - 1) / PC;
    int ps = pc * chunk;
    int pe = ps + chunk; if (pe > P) pe = P;
    int count = pe - ps;

    float bi[GC], sb[GC];
    unsigned bpp[GC];
#pragma unroll
    for (int j = 0; j < GC; ++j) { bi[j] = 0.f; sb[j] = 1.f; bpp[j] = (unsigned)(ps + tid); }

    for (int i = tid; i < count; i += 512) {
      int p0 = ps + i;
      int i1 = i + 256;
      int p1 = (i1 < count) ? ps + i1 : p0;  // clamped dup: strict > => no-op
      float4 q0 = ((const float4*)priors)[p0];
      float4 q1 = ((const float4*)priors)[p1];
      float ax1 = q0.x - q0.z * 0.5f, ay1 = q0.y - q0.w * 0.5f;
      float ax2 = q0.x + q0.z * 0.5f, ay2 = q0.y + q0.w * 0.5f;
      float aa = q0.z * q0.w;
      float bx1 = q1.x - q1.z * 0.5f, by1 = q1.y - q1.w * 0.5f;
      float bx2 = q1.x + q1.z * 0.5f, by2 = q1.y + q1.w * 0.5f;
      float ba = q1.z * q1.w;
#pragma unroll
      for (int j = 0; j < GC; ++j) {
        {
          float iw = fminf(gx2[j], ax2) - fmaxf(gx1[j], ax1);
          float ih = fminf(gy2[j], ay2) - fmaxf(gy1[j], ay1);
          float inter = fmaxf(iw, 0.f) * fmaxf(ih, 0.f);
          float S = ga[j] + aa;
          if (inter * sb[j] > bi[j] * S) { bi[j] = inter; sb[j] = S; bpp[j] = (unsigned)p0; }
        }
        {
          float iw = fminf(gx2[j], bx2) - fmaxf(gx1[j], bx1);
          float ih = fminf(gy2[j], by2) - fmaxf(gy1[j], by1);
          float inter = fmaxf(iw, 0.f) * fmaxf(ih, 0.f);
          float S = ga[j] + ba;
          if (inter * sb[j] > bi[j] * S) { bi[j] = inter; sb[j] = S; bpp[j] = (unsigned)p1; }
        }
      }
    }

    // divide early -> packed u64 (iou bits | ~p), LDS max tree
#pragma unroll
    for (int j = 0; j < GC; ++j) {
      float iou = bi[j] / (sb[j] - bi[j]);
      unsigned long long pk =
          ((unsigned long long)__float_as_uint(iou) << 32) | (unsigned)(~bpp[j]);
      sred[j * 256 + tid] = pk;
    }
    __syncthreads();
    {
      int j = tid >> 5, s = tid & 31;
      unsigned long long m = sred[j * 256 + s];
#pragma unroll
      for (int t = 1; t < 8; ++t) {
        unsigned long long v = sred[j * 256 + s + t * 32];
        if (v > m) m = v;
      }
      __syncthreads();
      sred[j * 256 + s] = m;
    }
    __syncthreads();
    if (tid < GC) {
      unsigned long long m = sred[tid * 256];
      for (int s = 1; s < 32; ++s) {
        unsigned long long v = sred[tid * 256 + s];
        if (v > m) m = v;
      }
      int g = g0 + tid;
      if (g < G) atomicMax(&bp[(size_t)b * G + g], m);
    }
  }
}

__global__ void k_scatter(const unsigned long long* __restrict__ bp,
                          float* __restrict__ bto, int* __restrict__ bti,
                          int* __restrict__ anyv, int P, int G) {
  int b = blockIdx.x, g = threadIdx.x;
  __shared__ unsigned spp[128];
  __shared__ int s_any;
  if (g == 0) s_any = 0;
  __syncthreads();
  unsigned long long m = bp[(size_t)b * G + g];
  unsigned pp = ~(unsigned)m;
  float val = __uint_as_float((unsigned)(m >> 32));
  bool ok = (m != 0ULL);
  float oldv = 0.f;
  if (ok) oldv = bto[(size_t)b * P + pp];
  spp[g] = ok ? pp : 0xFFFFFFFFu;
  if (ok && val >= 0.2f) s_any = 1;
  __syncthreads();
  bool win = ok;
  for (int g2 = g + 1; g2 < G; ++g2)
    if (spp[g2] == pp) win = false;
  if (win) {
    bto[(size_t)b * P + pp] = (val >= 0.2f) ? 2.0f : oldv;
    bti[(size_t)b * P + pp] = g;
  }
  __syncthreads();
  if (g == 0) anyv[b] = s_any;
}

__global__ __launch_bounds__(256) void k_main(
    const float* __restrict__ loc, const float* __restrict__ conf,
    const float* __restrict__ lm, const float* __restrict__ priors,
    const float* __restrict__ targets, const float* __restrict__ bto,
    const int* __restrict__ bti, const int* __restrict__ anyv,
    float* __restrict__ mine, unsigned* __restrict__ h1,
    double* __restrict__ pll, double* __restrict__ pllm,
    double* __restrict__ plc, double* __restrict__ msum,
    int* __restrict__ pnp, int P, int G, int PT) {
  int b = blockIdx.x / PT, tile = blockIdx.x % PT;
  int tid = threadIdx.x;
  int p = tile * 256 + tid;

  __shared__ float st[128 * 15];
  __shared__ unsigned hist[1024];
  __shared__ double rs[16];
  __shared__ int ri[4];

  for (int i = tid; i < G * 15; i += 256) st[i] = targets[(size_t)b * G * 15 + i];
  for (int i = tid; i < 1024; i += 256) hist[i] = 0;
  __syncthreads();

  double ll = 0, llm = 0, lc = 0, ms = 0;
  int np = 0;
  if (p < P) {
    size_t idx = (size_t)b * P + p;
    int av = anyv[b];
    float ov = bto[idx];
    int ti = bti[idx];
    bool pos = av && (ov >= 0.35f);

    float2 c = ((const float2*)conf)[idx];
    float mx = fmaxf(c.x, c.y);
    float lse = mx + logf(expf(c.x - mx) + expf(c.y - mx));
    float ce = lse - (pos ? c.y : c.x);
    float mv = pos ? 0.f : ce;
    mine[idx] = mv;
    ms = (double)mv;
    atomicAdd(&hist[__float_as_uint(mv) >> 21], 1u);

    if (pos) {
      np = 1;
      lc = (double)ce;
      float4 pr = ((const float4*)priors)[p];
      const float* t = st + ti * 15;
      float dx = 0.1f * pr.z, dy = 0.1f * pr.w;
      float gx = ((t[0] + t[2]) * 0.5f - pr.x) / dx;
      float gy = ((t[1] + t[3]) * 0.5f - pr.y) / dy;
      float gw = logf((t[2] - t[0]) / pr.z) * 5.0f;
      float gh = logf((t[3] - t[1]) / pr.w) * 5.0f;
      float4 ld = ((const float4*)loc)[idx];
      ll = (double)(sl1(ld.x - gx) + sl1(ld.y - gy) + sl1(ld.z - gw) +
                    sl1(ld.w - gh));
      const float2* lmd = (const float2*)lm + idx * 5;
      float s = 0.f;
#pragma unroll
      for (int j = 0; j < 5; ++j) {
        float2 lv = lmd[j];
        float ex = (t[4 + 2 * j] - pr.x) / dx;
        float ey = (t[5 + 2 * j] - pr.y) / dy;
        s += sl1(lv.x - ex) + sl1(lv.y - ey);
      }
      llm = (double)s;
    }
  }

  ll = dwave(ll);
  llm = dwave(llm);
  lc = dwave(lc);
  ms = dwave(ms);
#pragma unroll
  for (int o = 32; o; o >>= 1) np += __shfl_down(np, o);
  int lane = tid & 63, wid = tid >> 6;
  if (lane == 0) {
    rs[wid] = ll; rs[4 + wid] = llm; rs[8 + wid] = lc; rs[12 + wid] = ms;
    ri[wid] = np;
  }
  __syncthreads();
  if (tid == 0) {
    pll[blockIdx.x] = rs[0] + rs[1] + rs[2] + rs[3];
    pllm[blockIdx.x] = rs[4] + rs[5] + rs[6] + rs[7];
    plc[blockIdx.x] = rs[8] + rs[9] + rs[10] + rs[11];
    msum[blockIdx.x] = rs[12] + rs[13] + rs[14] + rs[15];
    pnp[blockIdx.x] = ri[0] + ri[1] + ri[2] + ri[3];
  }
  for (int i = tid; i < 1024; i += 256)
    if (hist[i]) atomicAdd(&h1[(size_t)b * 1024 + i], hist[i]);
}

__global__ __launch_bounds__(256) void k_sel1(
    const unsigned* __restrict__ h1, const int* __restrict__ pnp,
    const double* __restrict__ msum, int* __restrict__ num_pos,
    double* __restrict__ msum_b, int P, int PT, int* __restrict__ pfx1,
    int* __restrict__ k1) {
  int b = blockIdx.x, tid = threadIdx.x;
  __shared__ int sn[256];
  __shared__ double sm[256];
  int n = 0;
  double m = 0;
  for (int i = tid; i < PT; i += 256) { n += pnp[b * PT + i]; m += msum[b * PT + i]; }
  sn[tid] = n; sm[tid] = m;
  __syncthreads();
  for (int off = 128; off; off >>= 1) {
    if (tid < off) { sn[tid] += sn[tid + off]; sm[tid] += sm[tid + off]; }
    __syncthreads();
  }
  int npos = sn[0];
  if (tid == 0) { num_pos[b] = npos; msum_b[b] = sm[0]; }

  long long k = 7LL * (long long)npos;
  long long cap = P - 1;
  if (k <= 0) {
    if (tid == 0) { pfx1[b] = -1; k1[b] = 0; }
    return;
  }
  if (k >= cap) {
    // FAST PATH: every negative selected; loss_c_neg = sum(mine) = msum_b.
    if (tid == 0) { pfx1[b] = -2; k1[b] = 0; }
    return;
  }

  const unsigned* h = h1 + (size_t)b * 1024;
  __shared__ unsigned S[256];
  unsigned p0 = h[tid * 4], p1 = h[tid * 4 + 1], p2 = h[tid * 4 + 2],
           p3 = h[tid * 4 + 3];
  S[tid] = p0 + p1 + p2 + p3;
  __syncthreads();
  for (int off = 1; off < 256; off <<= 1) {
    unsigned add = (tid + off < 256) ? S[tid + off] : 0;
    __syncthreads();
    S[tid] += add;
    __syncthreads();
  }
  int cnt = __syncthreads_count((long long)S[tid] >= k);
  if (cnt == 0) {
    if (tid == 0) { pfx1[b] = -1; k1[b] = 0; }
    return;
  }
  int seg = cnt - 1;
  if (tid == seg) {
    long long cum = (seg + 1 < 256) ? (long long)S[seg + 1] : 0;
    unsigned hv[4] = {p0, p1, p2, p3};
    int bin = seg * 4;
    for (int j = 3; j >= 0; --j) {
      if (cum + hv[j] >= k) { bin = seg * 4 + j; break; }
      cum += hv[j];
    }
    pfx1[b] = bin;
    k1[b] = (int)(k - cum);
  }
}

// General-path radix select: one block per b, 3 in-LDS passes + final sum.
// Fast path / no-pos: early exit (pfs_b pre-zeroed).
__global__ __launch_bounds__(256) void k_select(
    const float* __restrict__ mine, const int* __restrict__ pfx1,
    const int* __restrict__ k1, double* __restrict__ pfs_b, int P) {
  int b = blockIdx.x, tid = threadIdx.x;
  int pf = pfx1[b];
  if (pf < 0) return;  // -2 fast (msum_b used), -1 none (pfs_b=0)
  const float* mrow = mine + (size_t)b * P;

  __shared__ unsigned hs[2048];
  __shared__ unsigned S[256];
  __shared__ int spf21, sk2;
  __shared__ unsigned stb;
  __shared__ double stie;
  __shared__ double rs[4];

  // pass A: hist over bits[20:10] within top bin pf
  for (int i = tid; i < 2048; i += 256) hs[i] = 0;
  __syncthreads();
  for (int i = tid; i < P; i += 256) {
    unsigned bits = __float_as_uint(mrow[i]);
    if ((int)(bits >> 21) == pf) atomicAdd(&hs[(bits >> 10) & 2047], 1u);
  }
  __syncthreads();
  {
    unsigned hv[8];
    unsigned s = 0;
#pragma unroll
    for (int j = 0; j < 8; ++j) { hv[j] = hs[tid * 8 + j]; s += hv[j]; }
    S[tid] = s;
    __syncthreads();
    for (int off = 1; off < 256; off <<= 1) {
      unsigned add = (tid + off < 256) ? S[tid + off] : 0;
      __syncthreads();
      S[tid] += add;
      __syncthreads();
    }
    long long k = (long long)k1[b];
    int cnt = __syncthreads_count((long long)S[tid] >= k);
    int seg = cnt - 1;
    if (tid == seg) {
      long long cum = (seg + 1 < 256) ? (long long)S[seg + 1] : 0;
      int bin = seg * 8;
      for (int j = 7; j >= 0; --j) {
        if (cum + hv[j] >= k) { bin = seg * 8 + j; break; }
        cum += hv[j];
      }
      spf21 = (pf << 11) | bin;
      sk2 = (int)(k - cum);
    }
  }
  __syncthreads();
  int pf21 = spf21;

  // pass B: hist over bits[9:0] within bin pf21
  for (int i = tid; i < 1024; i += 256) hs[i] = 0;
  __syncthreads();
  for (int i = tid; i < P; i += 256) {
    unsigned bits = __float_as_uint(mrow[i]);
    if ((int)(bits >> 10) == pf21) atomicAdd(&hs[bits & 1023], 1u);
  }
  __syncthreads();
  {
    unsigned p0 = hs[tid * 4], p1 = hs[tid * 4 + 1], p2 = hs[tid * 4 + 2],
             p3 = hs[tid * 4 + 3];
    S[tid] = p0 + p1 + p2 + p3;
    __syncthreads();
    for (int off = 1; off < 256; off <<= 1) {
      unsigned add = (tid + off < 256) ? S[tid + off] : 0;
      __syncthreads();
      S[tid] += add;
      __syncthreads();
    }
    long long k = (long long)sk2;
    int cnt = __syncthreads_count((long long)S[tid] >= k);
    int seg = cnt - 1;
    if (tid == seg) {
      long long cum = (seg + 1 < 256) ? (long long)S[seg + 1] : 0;
      unsigned hv[4] = {p0, p1, p2, p3};
      int bin = seg * 4;
      for (int j = 3; j >= 0; --j) {
        if (cum + hv[j] >= k) { bin = seg * 4 + j; break; }
        cum += hv[j];
      }
      unsigned tb = ((unsigned)pf21 << 10) | (unsigned)bin;
      stb = tb;
      stie = (double)(k - cum) * (double)__uint_as_float(tb);
    }
  }
  __syncthreads();

  // pass C: sum of mine strictly above threshold + tie contribution
  unsigned tb = stb;
  double v = 0.0;
  for (int i = tid; i < P; i += 256) {
    unsigned bits = __float_as_uint(mrow[i]);
    if (bits > tb) v += (double)__uint_as_float(bits);
  }
  v = dwave(v);
  int lane = tid & 63, wid = tid >> 6;
  if (lane == 0) rs[wid] = v;
  __syncthreads();
  if (tid == 0) pfs_b[b] = rs[0] + rs[1] + rs[2] + rs[3] + stie;
}

__global__ __launch_bounds__(256) void k_fin(
    const double* __restrict__ pll, const double* __restrict__ pllm,
    const double* __restrict__ plc, const double* __restrict__ pfs_b,
    const double* __restrict__ msum_b, const int* __restrict__ num_pos,
    const int* __restrict__ pfx1, float* __restrict__ out, int NBm, int B) {
  int tid = threadIdx.x;
  double a = 0, c = 0, d = 0, f = 0, n = 0;
  for (int i = tid; i < NBm; i += 256) { a += pll[i]; c += pllm[i]; d += plc[i]; }
  for (int i = tid; i < B; i += 256) {
    f += (pfx1[i] == -2) ? msum_b[i] : pfs_b[i];
    n += (double)num_pos[i];
  }
  a = dwave(a); c = dwave(c); d = dwave(d); f = dwave(f); n = dwave(n);
  __shared__ double rs[5 * 4];
  int lane = tid & 63, wid = tid >> 6;
  if (lane == 0) {
    rs[wid] = a; rs[4 + wid] = c; rs[8 + wid] = d;
    rs[12 + wid] = f; rs[16 + wid] = n;
  }
  __syncthreads();
  if (tid == 0) {
    double A = rs[0] + rs[1] + rs[2] + rs[3];
    double C = rs[4] + rs[5] + rs[6] + rs[7];
    double D = rs[8] + rs[9] + rs[10] + rs[11];
    double F = rs[12] + rs[13] + rs[14] + rs[15];
    double N = rs[16] + rs[17] + rs[18] + rs[19];
    if (N < 1.0) N = 1.0;
    out[0] = (float)(A / N);
    out[1] = (float)((D + F) / N);
    out[2] = (float)(C / N);
  }
}

extern "C" void kernel_launch(void* const* d_in, const int* in_sizes, int n_in,
                              void* d_out, int out_size, void* d_ws,
                              size_t ws_size, hipStream_t stream) {
  const float* loc = (const float*)d_in[0];
  const float* conf = (const float*)d_in[1];
  const float* lm = (const float*)d_in[2];
  const float* priors = (const float*)d_in[3];
  const float* targets = (const float*)d_in[4];

  int P = in_sizes[3] / 4;
  int B = in_sizes[0] / (4 * P);
  int G = in_sizes[4] / (15 * B);
  int PT = (P + 255) / 256;
  int PT3 = (P + 256 * PPI - 1) / (256 * PPI);
  int NBm = B * PT;
  int NGC = (G + GC - 1) / GC;
  int PC = 8;
  int NIOU = B * PT3;
  int NBP = B * NGC * PC;

  char* w = (char*)d_ws;
  size_t off = 0;
  // ---- zeroed region ----
  unsigned long long* bp = (unsigned long long*)(w + off);
  off += (size_t)B * G * 8;
  double* pfs_b = (double*)(w + off);
  off += (size_t)B * 8;
  int* ctrl = (int*)(w + off);
  off += (size_t)(8 * B) * 4;
  int* anyv = ctrl;
  int* num_pos = ctrl + B;
  int* pfx1 = ctrl + 2 * B;
  int* k1 = ctrl + 3 * B;
  unsigned* h1 = (unsigned*)(w + off);
  off += (size_t)B * 1024 * 4;
  size_t clear_bytes = off;
  // ---- non-zeroed region (written unconditionally) ----
  off = (off + 255) & ~(size_t)255;
  float* bto = (float*)(w + off);
  off += (size_t)B * P * 4;
  int* bti = (int*)(w + off);
  off += (size_t)B * P * 4;
  float* mine = (float*)(w + off);
  off += (size_t)B * P * 4;
  double* pll = (double*)(w + off);
  off += (size_t)NBm * 8;
  double* pllm = (double*)(w + off);
  off += (size_t)NBm * 8;
  double* plc = (double*)(w + off);
  off += (size_t)NBm * 8;
  double* msum = (double*)(w + off);
  off += (size_t)NBm * 8;
  double* msum_b = (double*)(w + off);
  off += (size_t)B * 8;
  int* pnp = (int*)(w + off);
  off += (size_t)NBm * 4;

  hipMemsetAsync(d_ws, 0, clear_bytes, stream);

  k_match<<<NIOU + NBP, 256, 0, stream>>>(priors, targets, bto, bti, bp, P, G,
                                          NIOU, PT3, NGC, PC);
  k_scatter<<<B, G, 0, stream>>>(bp, bto, bti, anyv, P, G);
  k_main<<<B * PT, 256, 0, stream>>>(loc, conf, lm, priors, targets, bto, bti,
                                     anyv, mine, h1, pll, pllm, plc, msum, pnp,
                                     P, G, PT);
  k_sel1<<<B, 256, 0, stream>>>(h1, pnp, msum, num_pos, msum_b, P, PT, pfx1,
                                k1);
  k_select<<<B, 256, 0, stream>>>(mine, pfx1, k1, pfs_b, P);
  k_fin<<<1, 256, 0, stream>>>(pll, pllm, plc, pfs_b, msum_b, num_pos, pfx1,
                               (float*)d_out, NBm, B);
}